// Round 1
// baseline (689.266 us; speedup 1.0000x reference)
//
#include <hip/hip_runtime.h>
#include <hip/hip_cooperative_groups.h>
#include <climits>

namespace cg = cooperative_groups;

#define VOXD 25
#define SLOT3 (VOXD*VOXD*VOXD)      // 15625
#define SLOTS (2*SLOT3)             // 31250
#define NCLS 8
#define NCODE 16
#define NBLK ((SLOTS + 255) / 256)  // 123
#define HB 2048                     // radix bins (11 bits)
#define FBK 64                      // fallback blocks per code (legacy path)
#define GSZ 16                      // threads per miss point
#define MPB (256 / GSZ)             // misses per block pass = 16
#define CSTRIDE SLOT3               // per-code bucket capacity

struct Scalars {
  double hub;
  double cosSum;
  int n1;
  int nmd;
  int binA, rA, binB, rB;
  float thresh;
  int done;
};

struct alignas(16) F4 { float x, y, z, w; };

__device__ __forceinline__ int voxslot(int b, int vx, int vy, int vz) {
  return ((b * VOXD + vx) * VOXD + vy) * VOXD + vz;
}

// ==========================================================================
// FUSED cooperative kernel: all 8 stages in one launch, grid.sync between.
// ==========================================================================
struct Params {
  const float* pred; const float* grid; const int* label; const int* batch;
  unsigned long long* vA; unsigned long long* vB; int* lmask;
  int* blCnt; float* blSum; int* codeCnt; int* missCnt; int* cntAB; int* ghist;
  Scalars* sc; float4* ctr; float4* pC; int* pSlot;
  unsigned* bufA; unsigned* bufB; float* tgt; float* mag; int* missPart;
  uint4* zbase; float* out;
  int zw16, n, mstride, fbk, r0, r1;
  double tfrac;
};

union SMemU {
  struct { int cnt[NCODE]; float sum[3*NCODE]; } s1;                    // scatter
  struct { int lc[NCODE]; int lb[NCODE]; } s2;                          // prep
  struct { int wCnt[4][NCODE]; int gBase[NCODE]; int h[HB]; } s3;       // targets
  struct { F4 tile[1024]; int stile[1024]; int h[HB]; } s4;             // fallback (28KB)
  struct { int h[HB]; } s6;                                             // select
  struct { double shH[256]; double shC[256]; int shN[256]; int shM[256]; } s7; // loss
};

// 256-thread (4-wave) inclusive block scan; ws[4] shared scratch.
__device__ __forceinline__ int block_scan256(int v, int* ws) {
  int lane = threadIdx.x & 63, w = threadIdx.x >> 6;
  int s = v;
  #pragma unroll
  for (int off = 1; off < 64; off <<= 1) {
    int t = __shfl_up(s, off, 64);
    if (lane >= off) s += t;
  }
  if (lane == 63) ws[w] = s;
  __syncthreads();
  int add = 0;
  #pragma unroll
  for (int q = 0; q < 4; ++q) if (q < w) add += ws[q];
  __syncthreads();   // protect ws for subsequent calls
  return s + add;
}

// Exact rank select within a coarse bin, 256-thread version of select_in_bin.
__device__ unsigned sel_in_bin256(const unsigned* __restrict__ buf, int cnt,
                                  int coarse, int rank, int* h, int* ws, int* misc) {
  int tid = threadIdx.x;
  for (int t = tid; t < HB; t += 256) h[t] = 0;
  __syncthreads();
  for (int t = tid; t < cnt; t += 256) atomicAdd(&h[(buf[t] >> 10) & 0x7FF], 1);
  __syncthreads();
  int base8 = tid * 8;
  int c[8], s = 0;
  #pragma unroll
  for (int k = 0; k < 8; ++k) { c[k] = h[base8 + k]; s += c[k]; }
  int incl = block_scan256(s, ws);
  int acc = incl - s;
  #pragma unroll
  for (int k = 0; k < 8; ++k) {
    if (rank >= acc && rank < acc + c[k]) { misc[4] = base8 + k; misc[5] = rank - acc; }
    acc += c[k];
  }
  __syncthreads();
  int subv = misc[4], subr = misc[5];
  for (int t = tid; t < 1024; t += 256) h[t] = 0;
  __syncthreads();
  for (int t = tid; t < cnt; t += 256) {
    unsigned v = buf[t];
    if ((int)((v >> 10) & 0x7FF) == subv) atomicAdd(&h[v & 0x3FF], 1);
  }
  __syncthreads();
  int base4 = tid * 4;
  int d4[4], s2 = 0;
  #pragma unroll
  for (int k = 0; k < 4; ++k) { d4[k] = h[base4 + k]; s2 += d4[k]; }
  int incl2 = block_scan256(s2, ws);
  int acc2 = incl2 - s2;
  #pragma unroll
  for (int k = 0; k < 4; ++k) {
    if (subr >= acc2 && subr < acc2 + d4[k]) misc[6] = base4 + k;
    acc2 += d4[k];
  }
  __syncthreads();
  int low = misc[6];
  return ((unsigned)coarse << 21) | ((unsigned)subv << 10) | (unsigned)low;
}

__global__ void __launch_bounds__(256, 4) k_fused(Params P) {
  cg::grid_group gg = cg::this_grid();
  __shared__ SMemU sm;
  __shared__ int s_ws[4];
  __shared__ int s_misc[8];
  int tid = threadIdx.x;
  int lane = tid & 63, w = tid >> 6;

  // ---------------- P0: zero-init the z-region ----------------
  {
    uint4 z = make_uint4(0u, 0u, 0u, 0u);
    int stride = (int)gridDim.x * 256;
    for (int i = (int)blockIdx.x * 256 + tid; i < P.zw16; i += stride) P.zbase[i] = z;
  }
  gg.sync();

  // ---------------- P1: scatter ----------------
  {
    if ((int)blockIdx.x * 256 < P.n) {
      if (tid < NCODE) sm.s1.cnt[tid] = 0;
      if (tid < 3 * NCODE) sm.s1.sum[tid] = 0.f;
      __syncthreads();
      int i = (int)blockIdx.x * 256 + tid;
      if (i < P.n) {
        float gx = P.grid[3*i], gy = P.grid[3*i+1], gz = P.grid[3*i+2];
        int ix = (int)gx, iy = (int)gy, iz = (int)gz;
        int vx = (int)floorf(gx * (1.0f/16.0f));
        int vy = (int)floorf(gy * (1.0f/16.0f));
        int vz = (int)floorf(gz * (1.0f/16.0f));
        int b = P.batch[i], l = P.label[i];
        int s = voxslot(b, vx, vy, vz);
        atomicAdd(&P.vA[s], ((unsigned long long)(unsigned)ix << 32) | (unsigned)iy);
        atomicAdd(&P.vB[s], ((unsigned long long)(unsigned)iz << 24) | 1ULL);
        atomicOr(&P.lmask[s], 1 << l);
        int bl = b * NCLS + l;
        atomicAdd(&sm.s1.cnt[bl], 1);
        atomicAdd(&sm.s1.sum[3*bl], gx);
        atomicAdd(&sm.s1.sum[3*bl+1], gy);
        atomicAdd(&sm.s1.sum[3*bl+2], gz);
      }
      __syncthreads();
      if (tid < NCODE && sm.s1.cnt[tid] != 0) atomicAdd(&P.blCnt[tid], sm.s1.cnt[tid]);
      if (tid < 3 * NCODE && sm.s1.sum[tid] != 0.f) atomicAdd(&P.blSum[tid], sm.s1.sum[tid]);
    }
  }
  gg.sync();

  // ---------------- P2: prep (decode slots, build per-code buckets) ----------------
  {
    if (blockIdx.x < NBLK) {
      if (tid < NCODE) sm.s2.lc[tid] = 0;
      __syncthreads();
      int s = (int)blockIdx.x * 256 + tid;
      int code = -1, lpos = 0;
      float4 v = make_float4(0.f, 0.f, 0.f, __int_as_float(-2));
      if (s < SLOTS) {
        unsigned long long bq = P.vB[s];
        unsigned c = (unsigned)(bq & 0xFFFFFFULL);
        if (c > 0) {
          unsigned long long aq = P.vA[s];
          float fc = (float)c;
          float cx = __fdiv_rn((float)(unsigned)(aq >> 32), fc);
          float cy = __fdiv_rn((float)(unsigned)(aq & 0xFFFFFFFFULL), fc);
          float cz = __fdiv_rn((float)(unsigned)(bq >> 24), fc);
          int m = P.lmask[s];
          bool pure = (m & (m - 1)) == 0;
          int lbl = __ffs(m) - 1;
          v = make_float4(cx, cy, cz, __int_as_float(pure ? lbl : -1));
          if (pure) {
            code = (s / SLOT3) * NCLS + lbl;
            lpos = atomicAdd(&sm.s2.lc[code], 1);
          }
        }
        P.ctr[s] = v;
      }
      __syncthreads();
      if (tid < NCODE) sm.s2.lb[tid] = (sm.s2.lc[tid] > 0) ? atomicAdd(&P.codeCnt[tid], sm.s2.lc[tid]) : 0;
      __syncthreads();
      if (code >= 0) {
        int pos = code * CSTRIDE + sm.s2.lb[code] + lpos;
        float c2 = __fadd_rn(__fadd_rn(__fmul_rn(v.x,v.x), __fmul_rn(v.y,v.y)),
                             __fmul_rn(v.z,v.z));
        P.pC[pos] = make_float4(v.x, v.y, v.z, c2);
        P.pSlot[pos] = s;
      }
    }
  }
  gg.sync();

  // ---------------- P3: probe targets + miss lists + hist ----------------
  {
    if ((int)blockIdx.x * 256 < P.n) {
      for (int t = tid; t < HB; t += 256) sm.s3.h[t] = 0;
      __syncthreads();
      int i = (int)blockIdx.x * 256 + tid;
      bool active = (i < P.n);
      bool miss = false;
      int mcode = -1;
      if (active) {
        float gx = P.grid[3*i], gy = P.grid[3*i+1], gz = P.grid[3*i+2];
        int vx = (int)floorf(gx * (1.0f/16.0f));
        int vy = (int)floorf(gy * (1.0f/16.0f));
        int vz = (int)floorf(gz * (1.0f/16.0f));
        int b = P.batch[i], l = P.label[i];
        int s = voxslot(b, vx, vy, vz);

        float4 own = P.ctr[s];
        bool purept = (__float_as_int(own.w) >= 0);

        int bl = b * NCLS + l;
        float fbc = (float)max(P.blCnt[bl], 1);
        float gcx = __fdiv_rn(P.blSum[3*bl],   fbc);
        float gcy = __fdiv_rn(P.blSum[3*bl+1], fbc);
        float gcz = __fdiv_rn(P.blSum[3*bl+2], fbc);

        float dx = __fsub_rn(gcx, own.x);
        float dy = __fsub_rn(gcy, own.y);
        float dz = __fsub_rn(gcz, own.z);
        int sgx = (dx > 0.f) ? 1 : ((dx < 0.f) ? -1 : 0);
        int sgy = (dy > 0.f) ? 1 : ((dy < 0.f) ? -1 : 0);
        int sgz = (dz > 0.f) ? 1 : ((dz < 0.f) ? -1 : 0);

        int ax1 = vx + sgx,     ay1 = vy + sgy,     az1 = vz + sgz;
        int ax2 = vx + 2 * sgx, ay2 = vy + 2 * sgy, az2 = vz + 2 * sgz;
        bool v1 = (unsigned)ax1 < (unsigned)VOXD && (unsigned)ay1 < (unsigned)VOXD &&
                  (unsigned)az1 < (unsigned)VOXD;
        bool v2 = (unsigned)ax2 < (unsigned)VOXD && (unsigned)ay2 < (unsigned)VOXD &&
                  (unsigned)az2 < (unsigned)VOXD;

        float4 q1 = make_float4(0.f, 0.f, 0.f, __int_as_float(-3));
        float4 q2 = q1;
        if (v1) q1 = P.ctr[voxslot(b, ax1, ay1, az1)];
        if (v2) q2 = P.ctr[voxslot(b, ax2, ay2, az2)];

        bool hit1 = v1 && (__float_as_int(q1.w) == l);
        bool hit2 = v2 && (__float_as_int(q2.w) == l);
        bool hit = hit1 || hit2;

        float tx = hit1 ? q1.x : (hit2 ? q2.x : gx);
        float ty = hit1 ? q1.y : (hit2 ? q2.y : gy);
        float tz = hit1 ? q1.z : (hit2 ? q2.z : gz);

        P.tgt[3*i] = tx; P.tgt[3*i+1] = ty; P.tgt[3*i+2] = tz;
        miss = (!purept && !hit);
        if (miss) {
          mcode = bl;
        } else {
          float tox = __fsub_rn(tx, gx), toy = __fsub_rn(ty, gy), toz = __fsub_rn(tz, gz);
          float ssq = __fadd_rn(__fadd_rn(__fmul_rn(tox,tox), __fmul_rn(toy,toy)),
                                __fmul_rn(toz,toz));
          float m = (ssq > 0.f) ? sqrtf(ssq) : 0.f;
          P.mag[i] = m;
          atomicAdd(&sm.s3.h[__float_as_uint(m) >> 21], 1);
        }
      }
      int myrank = 0;
      #pragma unroll
      for (int c = 0; c < NCODE; ++c) {
        unsigned long long mb = __ballot(mcode == c);
        if (lane == 0) sm.s3.wCnt[w][c] = __popcll(mb);
        if (mcode == c) myrank = __popcll(mb & ((1ULL << lane) - 1ULL));
      }
      __syncthreads();
      if (tid < NCODE) {
        int tot = sm.s3.wCnt[0][tid] + sm.s3.wCnt[1][tid] + sm.s3.wCnt[2][tid] + sm.s3.wCnt[3][tid];
        sm.s3.gBase[tid] = (tot > 0) ? atomicAdd(&P.missCnt[tid], tot) : 0;
      }
      __syncthreads();
      if (miss) {
        int base = sm.s3.gBase[mcode];
        #pragma unroll
        for (int q = 0; q < 4; ++q) if (q < w) base += sm.s3.wCnt[q][mcode];
        P.missPart[mcode * P.mstride + base + myrank] = i;
      }
      for (int t = tid; t < HB; t += 256) {
        int c = sm.s3.h[t];
        if (c != 0) atomicAdd(&P.ghist[t], c);
      }
    }
  }
  gg.sync();

  // ---------------- P4: fallback (nearest pure cluster, 16 thr/miss) ----------------
  {
    int cI = (int)blockIdx.x / P.fbk;
    int y  = (int)blockIdx.x % P.fbk;
    int mc = P.missCnt[cI];
    if (y * MPB < mc) {
      int cc = P.codeCnt[cI];
      int j0 = cI * CSTRIDE;
      const int* mlist = P.missPart + cI * P.mstride;
      int g8 = tid >> 4;
      int q = tid & (GSZ - 1);
      for (int t = tid; t < HB; t += 256) sm.s4.h[t] = 0;
      bool single = (cc <= 1024);
      if (single) {
        // tile fits entirely in LDS: load once, no per-pass reload/barriers
        for (int j = tid; j < cc; j += 256) {
          float4 t4 = P.pC[j0 + j];
          sm.s4.tile[j] = F4{t4.x, t4.y, t4.z, t4.w};
          sm.s4.stile[j] = P.pSlot[j0 + j];
        }
      }
      __syncthreads();
      for (int base = y * MPB; base < mc; base += P.fbk * MPB) {
        int t = base + g8;
        bool valid = (t < mc);
        int idx = 0;
        float gx = 0.f, gy = 0.f, gz = 0.f, p2 = 0.f;
        if (valid) {
          idx = mlist[t];
          gx = P.grid[3*idx]; gy = P.grid[3*idx+1]; gz = P.grid[3*idx+2];
          p2 = __fadd_rn(__fadd_rn(__fmul_rn(gx,gx), __fmul_rn(gy,gy)), __fmul_rn(gz,gz));
        }
        unsigned long long key = 0xFFFFFFFFFFFFFFFFULL;
        if (single) {
          if (valid) {
            #pragma unroll 4
            for (int j = q; j < cc; j += GSZ) {
              F4 cl = sm.s4.tile[j];
              float dot = __fadd_rn(__fadd_rn(__fmul_rn(gx,cl.x), __fmul_rn(gy,cl.y)),
                                    __fmul_rn(gz,cl.z));
              float d2 = __fadd_rn(__fsub_rn(p2, __fmul_rn(2.0f, dot)), cl.w);
              unsigned fb = __float_as_uint(d2);
              fb = (fb >> 31) ? ~fb : (fb | 0x80000000u);
              unsigned long long k2 = ((unsigned long long)fb << 32) | (unsigned)sm.s4.stile[j];
              if (k2 < key) key = k2;
            }
          }
        } else {
          for (int tb = 0; tb < cc; tb += 1024) {
            int m = min(1024, cc - tb);
            __syncthreads();
            for (int j = tid; j < m; j += 256) {
              float4 t4 = P.pC[j0 + tb + j];
              sm.s4.tile[j] = F4{t4.x, t4.y, t4.z, t4.w};
              sm.s4.stile[j] = P.pSlot[j0 + tb + j];
            }
            __syncthreads();
            if (valid) {
              #pragma unroll 4
              for (int j = q; j < m; j += GSZ) {
                F4 cl = sm.s4.tile[j];
                float dot = __fadd_rn(__fadd_rn(__fmul_rn(gx,cl.x), __fmul_rn(gy,cl.y)),
                                      __fmul_rn(gz,cl.z));
                float d2 = __fadd_rn(__fsub_rn(p2, __fmul_rn(2.0f, dot)), cl.w);
                unsigned fb = __float_as_uint(d2);
                fb = (fb >> 31) ? ~fb : (fb | 0x80000000u);
                unsigned long long k2 = ((unsigned long long)fb << 32) | (unsigned)sm.s4.stile[j];
                if (k2 < key) key = k2;
              }
            }
          }
        }
        #pragma unroll
        for (int off = 1; off < GSZ; off <<= 1) {
          unsigned long long o = __shfl_xor(key, off, 64);
          if (o < key) key = o;
        }
        if (valid && q == 0) {
          float mgv = 0.f;
          if (cc > 0) {
            int slot = (int)(unsigned)(key & 0xFFFFFFFFULL);
            float4 cl = P.ctr[slot];
            P.tgt[3*idx] = cl.x; P.tgt[3*idx+1] = cl.y; P.tgt[3*idx+2] = cl.z;
            float tox = __fsub_rn(cl.x, gx), toy = __fsub_rn(cl.y, gy), toz = __fsub_rn(cl.z, gz);
            float ssq = __fadd_rn(__fadd_rn(__fmul_rn(tox,tox), __fmul_rn(toy,toy)),
                                  __fmul_rn(toz,toz));
            mgv = (ssq > 0.f) ? sqrtf(ssq) : 0.f;
          }
          P.mag[idx] = mgv;
          atomicAdd(&sm.s4.h[__float_as_uint(mgv) >> 21], 1);
        }
        if (!single) __syncthreads();
      }
      __syncthreads();
      for (int t = tid; t < HB; t += 256) {
        int cv = sm.s4.h[t];
        if (cv != 0) atomicAdd(&P.ghist[t], cv);
      }
    }
  }
  gg.sync();

  // ---------------- P5: coarse-bin selection + candidate gather ----------------
  int binA = 0, rA = 0, binB = 0, rB = 0;
  {
    if ((int)blockIdx.x * 256 < P.n) {
      int base8 = tid * 8;
      int cbin[8];
      int s = 0;
      #pragma unroll
      for (int k = 0; k < 8; ++k) { cbin[k] = P.ghist[base8 + k]; s += cbin[k]; }
      int incl = block_scan256(s, s_ws);
      int lo = incl - s;
      if (P.r0 >= lo && P.r0 < lo + s) {
        int acc = lo;
        #pragma unroll
        for (int k = 0; k < 8; ++k) {
          if (P.r0 < acc + cbin[k]) { s_misc[0] = base8 + k; s_misc[1] = P.r0 - acc; break; }
          acc += cbin[k];
        }
      }
      if (P.r1 >= lo && P.r1 < lo + s) {
        int acc = lo;
        #pragma unroll
        for (int k = 0; k < 8; ++k) {
          if (P.r1 < acc + cbin[k]) { s_misc[2] = base8 + k; s_misc[3] = P.r1 - acc; break; }
          acc += cbin[k];
        }
      }
      __syncthreads();
      binA = s_misc[0]; rA = s_misc[1]; binB = s_misc[2]; rB = s_misc[3];

      int i = (int)blockIdx.x * 256 + tid;
      unsigned bits = 0;
      bool inA = false, inB = false;
      if (i < P.n) {
        bits = __float_as_uint(P.mag[i]);
        unsigned cb = bits >> 21;
        inA = (cb == (unsigned)binA);
        inB = (cb == (unsigned)binB);
      }
      {
        unsigned long long mb = __ballot(inA);
        int mcnt = __popcll(mb);
        int bs = 0;
        if (lane == 0 && mcnt > 0) bs = atomicAdd(&P.cntAB[0], mcnt);
        bs = __shfl(bs, 0, 64);
        if (inA) P.bufA[bs + __popcll(mb & ((1ULL << lane) - 1ULL))] = bits;
      }
      {
        unsigned long long mb = __ballot(inB);
        int mcnt = __popcll(mb);
        int bs = 0;
        if (lane == 0 && mcnt > 0) bs = atomicAdd(&P.cntAB[1], mcnt);
        bs = __shfl(bs, 0, 64);
        if (inB) P.bufB[bs + __popcll(mb & ((1ULL << lane) - 1ULL))] = bits;
      }
    }
  }
  gg.sync();

  // ---------------- P6: exact order statistics + lerp (block 0 only) ----------------
  {
    if (blockIdx.x == 0) {
      int ca = P.cntAB[0], cb2 = P.cntAB[1];
      unsigned va = sel_in_bin256(P.bufA, ca, binA, rA, sm.s6.h, s_ws, s_misc);
      __syncthreads();
      unsigned vb = sel_in_bin256(P.bufB, cb2, binB, rB, sm.s6.h, s_ws, s_misc);
      if (tid == 0) {
        double a = (double)__uint_as_float(va);
        double b = (double)__uint_as_float(vb);
        double th = (P.tfrac >= 0.5) ? (b - (b - a) * (1.0 - P.tfrac)) : (a + (b - a) * P.tfrac);
        P.sc->thresh = (float)th;
      }
    }
  }
  gg.sync();

  // ---------------- P7: masked huber + cosine reductions + finalize ----------------
  {
    bool ab = ((int)blockIdx.x * 256 < P.n);
    if (ab) {
      int i = (int)blockIdx.x * 256 + tid;
      double hub = 0.0, cs = 0.0;
      int c1 = 0, cmd = 0;
      if (i < P.n) {
        float th = P.sc->thresh;
        float m = P.mag[i];
        if (m <= th) {
          c1 = 1;
          float tox = __fsub_rn(P.tgt[3*i],   P.grid[3*i]);
          float toy = __fsub_rn(P.tgt[3*i+1], P.grid[3*i+1]);
          float toz = __fsub_rn(P.tgt[3*i+2], P.grid[3*i+2]);
          float px = P.pred[3*i], py = P.pred[3*i+1], pz = P.pred[3*i+2];
          float d0 = __fsub_rn(px, tox), d1 = __fsub_rn(py, toy), d2 = __fsub_rn(pz, toz);
          float a0 = fabsf(d0), a1 = fabsf(d1), a2 = fabsf(d2);
          float h0 = (a0 < 1.f) ? __fmul_rn(__fmul_rn(0.5f, d0), d0) : __fsub_rn(a0, 0.5f);
          float h1 = (a1 < 1.f) ? __fmul_rn(__fmul_rn(0.5f, d1), d1) : __fsub_rn(a1, 0.5f);
          float h2 = (a2 < 1.f) ? __fmul_rn(__fmul_rn(0.5f, d2), d2) : __fsub_rn(a2, 0.5f);
          hub = (double)h0 + (double)h1 + (double)h2;
          if (m > 0.f) {
            cmd = 1;
            float ps = __fadd_rn(__fadd_rn(__fmul_rn(px,px), __fmul_rn(py,py)), __fmul_rn(pz,pz));
            float pn = (ps > 0.f) ? sqrtf(ps) : 0.f;
            float dotp = __fadd_rn(__fadd_rn(__fmul_rn(px,tox), __fmul_rn(py,toy)),
                                   __fmul_rn(pz,toz));
            float den = fmaxf(__fmul_rn(pn, m), 1e-4f);
            cs = (double)__fdiv_rn(dotp, den);
          }
        }
      }
      sm.s7.shH[tid] = hub; sm.s7.shC[tid] = cs; sm.s7.shN[tid] = c1; sm.s7.shM[tid] = cmd;
      __syncthreads();
      for (int off = 128; off > 0; off >>= 1) {
        if (tid < off) {
          sm.s7.shH[tid] += sm.s7.shH[tid+off];
          sm.s7.shC[tid] += sm.s7.shC[tid+off];
          sm.s7.shN[tid] += sm.s7.shN[tid+off];
          sm.s7.shM[tid] += sm.s7.shM[tid+off];
        }
        __syncthreads();
      }
      if (tid == 0) {
        atomicAdd(&P.sc->hub, sm.s7.shH[0]);
        atomicAdd(&P.sc->cosSum, sm.s7.shC[0]);
        atomicAdd(&P.sc->n1, sm.s7.shN[0]);
        atomicAdd(&P.sc->nmd, sm.s7.shM[0]);
      }
    }
    if (tid == 0) {
      __threadfence();
      int d = atomicAdd(&P.sc->done, 1);
      if (d == (int)gridDim.x - 1) {
        double th_hub = atomicAdd(&P.sc->hub, 0.0);
        double th_cos = atomicAdd(&P.sc->cosSum, 0.0);
        int n1 = atomicAdd(&P.sc->n1, 0);
        int nmd = atomicAdd(&P.sc->nmd, 0);
        double l1 = (n1 > 0) ? th_hub / fmax((double)n1 * 3.0, 1.0) : 0.0;
        double ld = (nmd > 0) ? (1.0 - th_cos / fmax((double)nmd, 1.0)) : 0.0;
        P.out[0] = (float)l1;
        P.out[1] = (float)ld;
      }
    }
  }
}

// ==========================================================================
// LEGACY multi-kernel path (fallback if cooperative launch is unavailable).
// Identical to the previously-verified 163 µs pipeline.
// ==========================================================================

__device__ __forceinline__ int block_scan_i(int v, int* ws, int* total) {
  int lane = threadIdx.x & 63, w = threadIdx.x >> 6;
  int s = v;
  #pragma unroll
  for (int off = 1; off < 64; off <<= 1) {
    int t = __shfl_up(s, off, 64);
    if (lane >= off) s += t;
  }
  if (lane == 63) ws[w] = s;
  __syncthreads();
  if (threadIdx.x < 16) {
    int x = ws[threadIdx.x];
    #pragma unroll
    for (int off = 1; off < 16; off <<= 1) {
      int t = __shfl_up(x, off, 64);
      if (lane >= off) x += t;
    }
    ws[threadIdx.x] = x;
  }
  __syncthreads();
  if (w > 0) s += ws[w - 1];
  *total = ws[15];
  __syncthreads();
  return s;
}

__global__ void k_scatter(const float* __restrict__ grid, const int* __restrict__ label,
                          const int* __restrict__ batch,
                          unsigned long long* vA, unsigned long long* vB, int* lmask,
                          int* blCnt, float* blSum, int n) {
  __shared__ int sCnt[NCODE];
  __shared__ float sSum[3 * NCODE];
  int tid = threadIdx.x;
  if (tid < NCODE) sCnt[tid] = 0;
  if (tid < 3 * NCODE) sSum[tid] = 0.f;
  __syncthreads();
  int i = blockIdx.x * blockDim.x + tid;
  if (i < n) {
    float gx = grid[3*i], gy = grid[3*i+1], gz = grid[3*i+2];
    int ix = (int)gx, iy = (int)gy, iz = (int)gz;
    int vx = (int)floorf(gx * (1.0f/16.0f));
    int vy = (int)floorf(gy * (1.0f/16.0f));
    int vz = (int)floorf(gz * (1.0f/16.0f));
    int b = batch[i], l = label[i];
    int s = voxslot(b, vx, vy, vz);
    atomicAdd(&vA[s], ((unsigned long long)(unsigned)ix << 32) | (unsigned)iy);
    atomicAdd(&vB[s], ((unsigned long long)(unsigned)iz << 24) | 1ULL);
    atomicOr(&lmask[s], 1 << l);
    int bl = b * NCLS + l;
    atomicAdd(&sCnt[bl], 1);
    atomicAdd(&sSum[3*bl], gx); atomicAdd(&sSum[3*bl+1], gy); atomicAdd(&sSum[3*bl+2], gz);
  }
  __syncthreads();
  if (tid < NCODE && sCnt[tid] != 0) atomicAdd(&blCnt[tid], sCnt[tid]);
  if (tid < 3 * NCODE && sSum[tid] != 0.f) atomicAdd(&blSum[tid], sSum[tid]);
}

__global__ void k_prep(const unsigned long long* vA, const unsigned long long* vB,
                       const int* lmask, float4* ctr, float4* pC, int* pSlot,
                       int* codeCnt) {
  __shared__ int lc[NCODE];
  __shared__ int lb[NCODE];
  int tid = threadIdx.x;
  if (tid < NCODE) lc[tid] = 0;
  __syncthreads();
  int s = blockIdx.x * 256 + tid;
  int code = -1, lpos = 0;
  float4 v = make_float4(0.f, 0.f, 0.f, __int_as_float(-2));
  if (s < SLOTS) {
    unsigned long long bq = vB[s];
    unsigned c = (unsigned)(bq & 0xFFFFFFULL);
    if (c > 0) {
      unsigned long long aq = vA[s];
      float fc = (float)c;
      float cx = __fdiv_rn((float)(unsigned)(aq >> 32), fc);
      float cy = __fdiv_rn((float)(unsigned)(aq & 0xFFFFFFFFULL), fc);
      float cz = __fdiv_rn((float)(unsigned)(bq >> 24), fc);
      int m = lmask[s];
      bool pure = (m & (m - 1)) == 0;
      int lbl = __ffs(m) - 1;
      v = make_float4(cx, cy, cz, __int_as_float(pure ? lbl : -1));
      if (pure) {
        code = (s / SLOT3) * NCLS + lbl;
        lpos = atomicAdd(&lc[code], 1);
      }
    }
    ctr[s] = v;
  }
  __syncthreads();
  if (tid < NCODE) lb[tid] = (lc[tid] > 0) ? atomicAdd(&codeCnt[tid], lc[tid]) : 0;
  __syncthreads();
  if (code >= 0) {
    int pos = code * CSTRIDE + lb[code] + lpos;
    float c2 = __fadd_rn(__fadd_rn(__fmul_rn(v.x,v.x), __fmul_rn(v.y,v.y)),
                         __fmul_rn(v.z,v.z));
    pC[pos] = make_float4(v.x, v.y, v.z, c2);
    pSlot[pos] = s;
  }
}

__global__ void k_targets(const float* __restrict__ grid, const int* __restrict__ label,
                          const int* __restrict__ batch,
                          const float4* __restrict__ ctr,
                          const int* __restrict__ blCnt, const float* __restrict__ blSum,
                          float* tgt, float* mag, int* ghist,
                          int* missPart, int* missCnt, int mstride, int n) {
  __shared__ int wCnt[4][NCODE];
  __shared__ int gBase[NCODE];
  __shared__ int h[HB];
  int tid = threadIdx.x, lane = tid & 63, w = tid >> 6;
  for (int t = tid; t < HB; t += 256) h[t] = 0;
  __syncthreads();
  int i = blockIdx.x * blockDim.x + tid;
  bool active = (i < n);
  bool miss = false;
  int mcode = -1;

  if (active) {
    float gx = grid[3*i], gy = grid[3*i+1], gz = grid[3*i+2];
    int vx = (int)floorf(gx * (1.0f/16.0f));
    int vy = (int)floorf(gy * (1.0f/16.0f));
    int vz = (int)floorf(gz * (1.0f/16.0f));
    int b = batch[i], l = label[i];
    int s = voxslot(b, vx, vy, vz);

    float4 own = ctr[s];
    bool purept = (__float_as_int(own.w) >= 0);

    int bl = b * NCLS + l;
    float fbc = (float)max(blCnt[bl], 1);
    float gcx = __fdiv_rn(blSum[3*bl],   fbc);
    float gcy = __fdiv_rn(blSum[3*bl+1], fbc);
    float gcz = __fdiv_rn(blSum[3*bl+2], fbc);

    float dx = __fsub_rn(gcx, own.x);
    float dy = __fsub_rn(gcy, own.y);
    float dz = __fsub_rn(gcz, own.z);
    int sgx = (dx > 0.f) ? 1 : ((dx < 0.f) ? -1 : 0);
    int sgy = (dy > 0.f) ? 1 : ((dy < 0.f) ? -1 : 0);
    int sgz = (dz > 0.f) ? 1 : ((dz < 0.f) ? -1 : 0);

    int ax1 = vx + sgx,     ay1 = vy + sgy,     az1 = vz + sgz;
    int ax2 = vx + 2 * sgx, ay2 = vy + 2 * sgy, az2 = vz + 2 * sgz;
    bool v1 = (unsigned)ax1 < (unsigned)VOXD && (unsigned)ay1 < (unsigned)VOXD &&
              (unsigned)az1 < (unsigned)VOXD;
    bool v2 = (unsigned)ax2 < (unsigned)VOXD && (unsigned)ay2 < (unsigned)VOXD &&
              (unsigned)az2 < (unsigned)VOXD;

    float4 q1 = make_float4(0.f, 0.f, 0.f, __int_as_float(-3));
    float4 q2 = q1;
    if (v1) q1 = ctr[voxslot(b, ax1, ay1, az1)];
    if (v2) q2 = ctr[voxslot(b, ax2, ay2, az2)];

    bool hit1 = v1 && (__float_as_int(q1.w) == l);
    bool hit2 = v2 && (__float_as_int(q2.w) == l);
    bool hit = hit1 || hit2;

    float tx = hit1 ? q1.x : (hit2 ? q2.x : gx);
    float ty = hit1 ? q1.y : (hit2 ? q2.y : gy);
    float tz = hit1 ? q1.z : (hit2 ? q2.z : gz);

    tgt[3*i] = tx; tgt[3*i+1] = ty; tgt[3*i+2] = tz;
    miss = (!purept && !hit);
    if (miss) {
      mcode = bl;
    } else {
      float tox = __fsub_rn(tx, gx), toy = __fsub_rn(ty, gy), toz = __fsub_rn(tz, gz);
      float ssq = __fadd_rn(__fadd_rn(__fmul_rn(tox,tox), __fmul_rn(toy,toy)),
                            __fmul_rn(toz,toz));
      float m = (ssq > 0.f) ? sqrtf(ssq) : 0.f;
      mag[i] = m;
      atomicAdd(&h[__float_as_uint(m) >> 21], 1);
    }
  }
  int myrank = 0;
  #pragma unroll
  for (int c = 0; c < NCODE; ++c) {
    unsigned long long mb = __ballot(mcode == c);
    if (lane == 0) wCnt[w][c] = __popcll(mb);
    if (mcode == c) myrank = __popcll(mb & ((1ULL << lane) - 1ULL));
  }
  __syncthreads();
  if (tid < NCODE) {
    int tot = wCnt[0][tid] + wCnt[1][tid] + wCnt[2][tid] + wCnt[3][tid];
    gBase[tid] = (tot > 0) ? atomicAdd(&missCnt[tid], tot) : 0;
  }
  __syncthreads();
  if (miss) {
    int base = gBase[mcode];
    for (int q = 0; q < 4; ++q) if (q < w) base += wCnt[q][mcode];
    missPart[mcode * mstride + base + myrank] = i;
  }
  for (int t = tid; t < HB; t += 256) {
    int c = h[t];
    if (c != 0) atomicAdd(&ghist[t], c);
  }
}

__global__ void __launch_bounds__(256) k_fallback(
    const float* __restrict__ grid,
    const float4* __restrict__ pC, const int* __restrict__ pSlot,
    const float4* __restrict__ ctr,
    const int* __restrict__ codeCnt,
    const int* __restrict__ missPart, const int* __restrict__ missCnt,
    float* tgt, float* mag, int* ghist, int mstride) {
  __shared__ float4 tile[1024];
  __shared__ int stile[1024];
  __shared__ int h[HB];
  int c = blockIdx.x / FBK;
  int y = blockIdx.x % FBK;
  int mc = missCnt[c];
  if (y * MPB >= mc) return;
  int cc = codeCnt[c];
  int j0 = c * CSTRIDE;
  const int* mlist = missPart + c * mstride;
  int g = threadIdx.x >> 4;
  int q = threadIdx.x & (GSZ - 1);
  for (int t = threadIdx.x; t < HB; t += 256) h[t] = 0;

  for (int base = y * MPB; base < mc; base += FBK * MPB) {
    int t = base + g;
    bool valid = (t < mc);
    int idx = 0;
    float gx = 0.f, gy = 0.f, gz = 0.f, p2 = 0.f;
    if (valid) {
      idx = mlist[t];
      gx = grid[3*idx]; gy = grid[3*idx+1]; gz = grid[3*idx+2];
      p2 = __fadd_rn(__fadd_rn(__fmul_rn(gx,gx), __fmul_rn(gy,gy)), __fmul_rn(gz,gz));
    }
    unsigned long long key = 0xFFFFFFFFFFFFFFFFULL;
    for (int tb = 0; tb < cc; tb += 1024) {
      int m = min(1024, cc - tb);
      __syncthreads();
      for (int j = threadIdx.x; j < m; j += 256) {
        tile[j] = pC[j0 + tb + j];
        stile[j] = pSlot[j0 + tb + j];
      }
      __syncthreads();
      if (valid) {
        #pragma unroll 4
        for (int j = q; j < m; j += GSZ) {
          float4 cl = tile[j];
          float dot = __fadd_rn(__fadd_rn(__fmul_rn(gx,cl.x), __fmul_rn(gy,cl.y)),
                                __fmul_rn(gz,cl.z));
          float d2 = __fadd_rn(__fsub_rn(p2, __fmul_rn(2.0f, dot)), cl.w);
          unsigned fb = __float_as_uint(d2);
          fb = (fb >> 31) ? ~fb : (fb | 0x80000000u);
          unsigned long long k2 = ((unsigned long long)fb << 32) | (unsigned)stile[j];
          if (k2 < key) key = k2;
        }
      }
    }
    #pragma unroll
    for (int off = 1; off < GSZ; off <<= 1) {
      unsigned long long o = __shfl_xor(key, off, 64);
      if (o < key) key = o;
    }
    if (valid && q == 0) {
      float m = 0.f;
      if (cc > 0) {
        int slot = (int)(unsigned)(key & 0xFFFFFFFFULL);
        float4 cl = ctr[slot];
        tgt[3*idx] = cl.x; tgt[3*idx+1] = cl.y; tgt[3*idx+2] = cl.z;
        float tox = __fsub_rn(cl.x, gx), toy = __fsub_rn(cl.y, gy), toz = __fsub_rn(cl.z, gz);
        float ssq = __fadd_rn(__fadd_rn(__fmul_rn(tox,tox), __fmul_rn(toy,toy)),
                              __fmul_rn(toz,toz));
        m = (ssq > 0.f) ? sqrtf(ssq) : 0.f;
      }
      mag[idx] = m;
      atomicAdd(&h[__float_as_uint(m) >> 21], 1);
    }
    __syncthreads();
  }
  for (int t = threadIdx.x; t < HB; t += 256) {
    int cv = h[t];
    if (cv != 0) atomicAdd(&ghist[t], cv);
  }
}

__global__ void k_gather(const float* __restrict__ mag, const int* __restrict__ ghist,
                         Scalars* sc, unsigned* bufA, unsigned* bufB, int* cntAB,
                         int n, int r0, int r1) {
  __shared__ int ws[4];
  __shared__ int sBinA, sRA, sBinB, sRB;
  int tid = threadIdx.x, lane = tid & 63, w = tid >> 6;
  int base8 = tid * 8;
  int cbin[8];
  int s = 0;
  #pragma unroll
  for (int k = 0; k < 8; ++k) { cbin[k] = ghist[base8 + k]; s += cbin[k]; }
  int incl = s;
  #pragma unroll
  for (int off = 1; off < 64; off <<= 1) {
    int t = __shfl_up(incl, off, 64);
    if (lane >= off) incl += t;
  }
  if (lane == 63) ws[w] = incl;
  __syncthreads();
  int wofs = 0;
  #pragma unroll
  for (int qq = 0; qq < 4; ++qq) if (qq < w) wofs += ws[qq];
  int lo = wofs + incl - s;
  if (r0 >= lo && r0 < lo + s) {
    int acc = lo;
    #pragma unroll
    for (int k = 0; k < 8; ++k) {
      if (r0 < acc + cbin[k]) { sBinA = base8 + k; sRA = r0 - acc; break; }
      acc += cbin[k];
    }
  }
  if (r1 >= lo && r1 < lo + s) {
    int acc = lo;
    #pragma unroll
    for (int k = 0; k < 8; ++k) {
      if (r1 < acc + cbin[k]) { sBinB = base8 + k; sRB = r1 - acc; break; }
      acc += cbin[k];
    }
  }
  __syncthreads();
  if (blockIdx.x == 0 && tid == 0) {
    sc->binA = sBinA; sc->rA = sRA; sc->binB = sBinB; sc->rB = sRB;
  }
  int binA = sBinA, binB = sBinB;

  int i = blockIdx.x * blockDim.x + tid;
  unsigned bits = 0;
  bool inA = false, inB = false;
  if (i < n) {
    bits = __float_as_uint(mag[i]);
    unsigned cb = bits >> 21;
    inA = (cb == (unsigned)binA);
    inB = (cb == (unsigned)binB);
  }
  {
    unsigned long long mb = __ballot(inA);
    int mc = __popcll(mb);
    int bs = 0;
    if (lane == 0 && mc > 0) bs = atomicAdd(&cntAB[0], mc);
    bs = __shfl(bs, 0, 64);
    if (inA) bufA[bs + __popcll(mb & ((1ULL << lane) - 1ULL))] = bits;
  }
  {
    unsigned long long mb = __ballot(inB);
    int mc = __popcll(mb);
    int bs = 0;
    if (lane == 0 && mc > 0) bs = atomicAdd(&cntAB[1], mc);
    bs = __shfl(bs, 0, 64);
    if (inB) bufB[bs + __popcll(mb & ((1ULL << lane) - 1ULL))] = bits;
  }
}

__device__ unsigned select_in_bin(const unsigned* __restrict__ buf, int cnt,
                                  int coarse, int rank, int* h, int* ws) {
  __shared__ int sSub, sSubR, sLow;
  for (int t = threadIdx.x; t < HB; t += 1024) h[t] = 0;
  __syncthreads();
  for (int t = threadIdx.x; t < cnt; t += 1024)
    atomicAdd(&h[(buf[t] >> 10) & 0x7FF], 1);
  __syncthreads();
  int t = threadIdx.x;
  int s0 = h[2*t], s1 = h[2*t+1];
  int tot;
  int incl = block_scan_i(s0 + s1, ws, &tot);
  int b1 = incl - s1, b0 = b1 - s0;
  if (rank >= b0 && rank < b0 + s0) { sSub = 2*t;   sSubR = rank - b0; }
  if (rank >= b1 && rank < b1 + s1) { sSub = 2*t+1; sSubR = rank - b1; }
  __syncthreads();
  int subv = sSub, subr = sSubR;
  h[t] = 0;
  __syncthreads();
  for (int q = threadIdx.x; q < cnt; q += 1024) {
    unsigned v = buf[q];
    if ((int)((v >> 10) & 0x7FF) == subv) atomicAdd(&h[v & 0x3FF], 1);
  }
  __syncthreads();
  int c = h[t];
  int tot2;
  int incl2 = block_scan_i(c, ws, &tot2);
  int lb = incl2 - c;
  if (subr >= lb && subr < lb + c) sLow = t;
  __syncthreads();
  return ((unsigned)coarse << 21) | ((unsigned)subv << 10) | (unsigned)sLow;
}

__global__ void __launch_bounds__(1024) k_sel(const unsigned* __restrict__ bufA,
                                              const unsigned* __restrict__ bufB,
                                              const int* __restrict__ cntAB,
                                              Scalars* sc, double tfrac) {
  __shared__ int h[HB];
  __shared__ int ws[16];
  unsigned va = select_in_bin(bufA, cntAB[0], sc->binA, sc->rA, h, ws);
  __syncthreads();
  unsigned vb = select_in_bin(bufB, cntAB[1], sc->binB, sc->rB, h, ws);
  if (threadIdx.x == 0) {
    double a = (double)__uint_as_float(va);
    double b = (double)__uint_as_float(vb);
    double th = (tfrac >= 0.5) ? (b - (b - a) * (1.0 - tfrac)) : (a + (b - a) * tfrac);
    sc->thresh = (float)th;
  }
}

__global__ void k_loss(const float* __restrict__ pred, const float* __restrict__ grid,
                       const float* __restrict__ tgt, const float* __restrict__ mag,
                       Scalars* sc, float* out, int n) {
  __shared__ double shH[256];
  __shared__ double shC[256];
  __shared__ int shN[256];
  __shared__ int shM[256];
  int tid = threadIdx.x;
  int i = blockIdx.x * blockDim.x + tid;
  double hub = 0.0, cs = 0.0;
  int c1 = 0, cmd = 0;
  if (i < n) {
    float th = sc->thresh;
    float m = mag[i];
    if (m <= th) {
      c1 = 1;
      float tox = __fsub_rn(tgt[3*i],   grid[3*i]);
      float toy = __fsub_rn(tgt[3*i+1], grid[3*i+1]);
      float toz = __fsub_rn(tgt[3*i+2], grid[3*i+2]);
      float px = pred[3*i], py = pred[3*i+1], pz = pred[3*i+2];
      float d0 = __fsub_rn(px, tox), d1 = __fsub_rn(py, toy), d2 = __fsub_rn(pz, toz);
      float a0 = fabsf(d0), a1 = fabsf(d1), a2 = fabsf(d2);
      float h0 = (a0 < 1.f) ? __fmul_rn(__fmul_rn(0.5f, d0), d0) : __fsub_rn(a0, 0.5f);
      float h1 = (a1 < 1.f) ? __fmul_rn(__fmul_rn(0.5f, d1), d1) : __fsub_rn(a1, 0.5f);
      float h2 = (a2 < 1.f) ? __fmul_rn(__fmul_rn(0.5f, d2), d2) : __fsub_rn(a2, 0.5f);
      hub = (double)h0 + (double)h1 + (double)h2;
      if (m > 0.f) {
        cmd = 1;
        float ps = __fadd_rn(__fadd_rn(__fmul_rn(px,px), __fmul_rn(py,py)), __fmul_rn(pz,pz));
        float pn = (ps > 0.f) ? sqrtf(ps) : 0.f;
        float dotp = __fadd_rn(__fadd_rn(__fmul_rn(px,tox), __fmul_rn(py,toy)),
                               __fmul_rn(pz,toz));
        float den = fmaxf(__fmul_rn(pn, m), 1e-4f);
        cs = (double)__fdiv_rn(dotp, den);
      }
    }
  }
  shH[tid] = hub; shC[tid] = cs; shN[tid] = c1; shM[tid] = cmd;
  __syncthreads();
  for (int off = 128; off > 0; off >>= 1) {
    if (tid < off) {
      shH[tid] += shH[tid+off];
      shC[tid] += shC[tid+off];
      shN[tid] += shN[tid+off];
      shM[tid] += shM[tid+off];
    }
    __syncthreads();
  }
  if (tid == 0) {
    atomicAdd(&sc->hub, shH[0]);
    atomicAdd(&sc->cosSum, shC[0]);
    atomicAdd(&sc->n1, shN[0]);
    atomicAdd(&sc->nmd, shM[0]);
    __threadfence();
    int d = atomicAdd(&sc->done, 1);
    if (d == (int)gridDim.x - 1) {
      __threadfence();
      double th_hub = atomicAdd(&sc->hub, 0.0);
      double th_cos = atomicAdd(&sc->cosSum, 0.0);
      int n1 = atomicAdd(&sc->n1, 0);
      int nmd = atomicAdd(&sc->nmd, 0);
      double l1 = (n1 > 0) ? th_hub / fmax((double)n1 * 3.0, 1.0) : 0.0;
      double ld = (nmd > 0) ? (1.0 - th_cos / fmax((double)nmd, 1.0)) : 0.0;
      out[0] = (float)l1;
      out[1] = (float)ld;
    }
  }
}

extern "C" void kernel_launch(void* const* d_in, const int* in_sizes, int n_in,
                              void* d_out, int out_size, void* d_ws, size_t ws_size,
                              hipStream_t stream) {
  const float* pred  = (const float*)d_in[0];
  const float* grid  = (const float*)d_in[1];
  const int*   label = (const int*)d_in[2];
  const int*   batch = (const int*)d_in[3];
  int n = in_sizes[2];
  int mstride = n / 4;

  char* p = (char*)d_ws;
  auto take = [&](size_t bytes) -> char* {
    char* r = p;
    p += (bytes + 255) & ~(size_t)255;
    return r;
  };
  // ---- zero-init region ----
  char* zbase = p;
  unsigned long long* vA = (unsigned long long*)take((size_t)SLOTS*8);
  unsigned long long* vB = (unsigned long long*)take((size_t)SLOTS*8);
  int*    lmask    = (int*)   take((size_t)SLOTS*4);
  int*    codeCnt  = (int*)   take(NCODE*4);
  int*    missCnt  = (int*)   take(NCODE*4);
  int*    blCnt    = (int*)   take(16*4);
  float*  blSum    = (float*) take(48*4);
  int*    cntAB    = (int*)   take(2*4);
  int*    ghist    = (int*)   take((size_t)HB*4);
  Scalars* sc      = (Scalars*)take(sizeof(Scalars));
  size_t zbytes = (size_t)(p - zbase);
  // ---- uninitialized buffers ----
  float4* ctr      = (float4*)take((size_t)SLOTS*16);
  float4* pC       = (float4*)take((size_t)NCODE*CSTRIDE*16);
  int*    pSlot    = (int*)   take((size_t)NCODE*CSTRIDE*4);
  unsigned* bufA   = (unsigned*)take((size_t)n*4);
  unsigned* bufB   = (unsigned*)take((size_t)n*4);
  float*  tgt      = (float*) take((size_t)n*3*4);
  float*  mag      = (float*) take((size_t)n*4);
  int*    missPart = (int*)   take((size_t)NCODE*mstride*4);

  int nb = (n + 255) / 256;

  double vi = 0.99 * (double)(n - 1);
  int r0 = (int)vi;
  int r1 = r0 + 1; if (r1 > n - 1) r1 = n - 1;
  double tfrac = vi - (double)r0;

  // ---- fused cooperative path ----
  static int s_nbk = -1;
  if (s_nbk < 0) {
    int b = 0;
    if (hipOccupancyMaxActiveBlocksPerMultiprocessor(&b, (const void*)k_fused, 256, 0)
            != hipSuccess || b < 1) b = 0;
    long nbk = (long)b * 256;     // 256 CUs on MI355X
    if (nbk > 1024) nbk = 1024;   // keep the proven 16-codes x 64-blocks fallback shape
    nbk -= nbk % NCODE;
    s_nbk = (int)nbk;
  }
  if (s_nbk >= NCODE && (long)s_nbk * 256 >= (long)n) {
    Params Pm;
    Pm.pred = pred; Pm.grid = grid; Pm.label = label; Pm.batch = batch;
    Pm.vA = vA; Pm.vB = vB; Pm.lmask = lmask;
    Pm.blCnt = blCnt; Pm.blSum = blSum; Pm.codeCnt = codeCnt; Pm.missCnt = missCnt;
    Pm.cntAB = cntAB; Pm.ghist = ghist; Pm.sc = sc;
    Pm.ctr = ctr; Pm.pC = pC; Pm.pSlot = pSlot;
    Pm.bufA = bufA; Pm.bufB = bufB; Pm.tgt = tgt; Pm.mag = mag; Pm.missPart = missPart;
    Pm.zbase = (uint4*)zbase; Pm.out = (float*)d_out;
    Pm.zw16 = (int)(zbytes / 16);
    Pm.n = n; Pm.mstride = mstride; Pm.fbk = s_nbk / NCODE;
    Pm.r0 = r0; Pm.r1 = r1; Pm.tfrac = tfrac;
    void* kargs[] = { (void*)&Pm };
    if (hipLaunchCooperativeKernel((const void*)k_fused, dim3(s_nbk), dim3(256),
                                   kargs, 0, stream) == hipSuccess)
      return;
    (void)hipGetLastError();   // clear error, fall through to legacy path
  }

  // ---- legacy 8-dispatch path (previously verified, 163 µs) ----
  hipMemsetAsync(zbase, 0, zbytes, stream);
  k_scatter<<<nb, 256, 0, stream>>>(grid, label, batch, vA, vB, lmask,
                                    blCnt, blSum, n);
  k_prep<<<NBLK, 256, 0, stream>>>(vA, vB, lmask, ctr, pC, pSlot, codeCnt);
  k_targets<<<nb, 256, 0, stream>>>(grid, label, batch, ctr, blCnt, blSum,
                                    tgt, mag, ghist, missPart, missCnt, mstride, n);
  k_fallback<<<NCODE * FBK, 256, 0, stream>>>(grid, pC, pSlot, ctr, codeCnt,
                                              missPart, missCnt, tgt, mag, ghist,
                                              mstride);
  k_gather<<<nb, 256, 0, stream>>>(mag, ghist, sc, bufA, bufB, cntAB, n, r0, r1);
  k_sel<<<1, 1024, 0, stream>>>(bufA, bufB, cntAB, sc, tfrac);
  k_loss<<<nb, 256, 0, stream>>>(pred, grid, tgt, mag, sc, (float*)d_out, n);
}

// Round 2
// 221.296 us; speedup vs baseline: 3.1147x; 3.1147x over previous
//
#include <hip/hip_runtime.h>
#include <climits>

#define VOXD 25
#define SLOT3 (VOXD*VOXD*VOXD)      // 15625
#define SLOTS (2*SLOT3)             // 31250
#define NCLS 8
#define NCODE 16
#define NBLK ((SLOTS + 255) / 256)  // 123
#define HB 2048                     // radix bins (11 bits)
#define GSZ 16                      // threads per miss point in fallback
#define CSTRIDE SLOT3               // per-code bucket capacity

struct Scalars {
  double hub;
  double cosSum;
  int n1;
  int nmd;
  float thresh;
  int done;
};

__device__ __forceinline__ int voxslot(int b, int vx, int vy, int vz) {
  return ((b * VOXD + vx) * VOXD + vy) * VOXD + vz;
}

// 256-thread (4-wave) inclusive block scan; ws[4] shared scratch.
// Trailing barrier makes ws immediately reusable by the next call.
__device__ __forceinline__ int block_scan256(int v, int* ws) {
  int lane = threadIdx.x & 63, w = threadIdx.x >> 6;
  int s = v;
  #pragma unroll
  for (int off = 1; off < 64; off <<= 1) {
    int t = __shfl_up(s, off, 64);
    if (lane >= off) s += t;
  }
  if (lane == 63) ws[w] = s;
  __syncthreads();
  int add = 0;
  #pragma unroll
  for (int q = 0; q < 4; ++q) if (q < w) add += ws[q];
  __syncthreads();
  return s + add;
}

// ---------------- K1: scatter with packed integer-exact atomics ------------------
__global__ void k_scatter(const float* __restrict__ grid, const int* __restrict__ label,
                          const int* __restrict__ batch,
                          unsigned long long* vA, unsigned long long* vB, int* lmask,
                          int* blCnt, float* blSum, int n) {
  __shared__ int sCnt[NCODE];
  __shared__ float sSum[3 * NCODE];
  int tid = threadIdx.x;
  if (tid < NCODE) sCnt[tid] = 0;
  if (tid < 3 * NCODE) sSum[tid] = 0.f;
  __syncthreads();
  int i = blockIdx.x * blockDim.x + tid;
  if (i < n) {
    float gx = grid[3*i], gy = grid[3*i+1], gz = grid[3*i+2];
    int ix = (int)gx, iy = (int)gy, iz = (int)gz;   // coords are exact small ints
    int vx = (int)floorf(gx * (1.0f/16.0f));
    int vy = (int)floorf(gy * (1.0f/16.0f));
    int vz = (int)floorf(gz * (1.0f/16.0f));
    int b = batch[i], l = label[i];
    int s = voxslot(b, vx, vy, vz);
    atomicAdd(&vA[s], ((unsigned long long)(unsigned)ix << 32) | (unsigned)iy);
    atomicAdd(&vB[s], ((unsigned long long)(unsigned)iz << 24) | 1ULL);
    atomicOr(&lmask[s], 1 << l);
    int bl = b * NCLS + l;
    atomicAdd(&sCnt[bl], 1);
    atomicAdd(&sSum[3*bl], gx); atomicAdd(&sSum[3*bl+1], gy); atomicAdd(&sSum[3*bl+2], gz);
  }
  __syncthreads();
  if (tid < NCODE && sCnt[tid] != 0) atomicAdd(&blCnt[tid], sCnt[tid]);
  if (tid < 3 * NCODE && sSum[tid] != 0.f) atomicAdd(&blSum[tid], sSum[tid]);
}

// ---------------- K2: decode tables -> slot float4 + per-code bucket append ------
__global__ void k_prep(const unsigned long long* vA, const unsigned long long* vB,
                       const int* lmask, float4* ctr, float4* pC, int* pSlot,
                       int* codeCnt) {
  __shared__ int lc[NCODE];
  __shared__ int lb[NCODE];
  int tid = threadIdx.x;
  if (tid < NCODE) lc[tid] = 0;
  __syncthreads();
  int s = blockIdx.x * 256 + tid;
  int code = -1, lpos = 0;
  float4 v = make_float4(0.f, 0.f, 0.f, __int_as_float(-2));
  if (s < SLOTS) {
    unsigned long long bq = vB[s];
    unsigned c = (unsigned)(bq & 0xFFFFFFULL);
    if (c > 0) {
      unsigned long long aq = vA[s];
      float fc = (float)c;
      float cx = __fdiv_rn((float)(unsigned)(aq >> 32), fc);
      float cy = __fdiv_rn((float)(unsigned)(aq & 0xFFFFFFFFULL), fc);
      float cz = __fdiv_rn((float)(unsigned)(bq >> 24), fc);
      int m = lmask[s];
      bool pure = (m & (m - 1)) == 0;
      int lbl = __ffs(m) - 1;
      v = make_float4(cx, cy, cz, __int_as_float(pure ? lbl : -1));
      if (pure) {
        code = (s / SLOT3) * NCLS + lbl;
        lpos = atomicAdd(&lc[code], 1);
      }
    }
    ctr[s] = v;
  }
  __syncthreads();
  if (tid < NCODE) lb[tid] = (lc[tid] > 0) ? atomicAdd(&codeCnt[tid], lc[tid]) : 0;
  __syncthreads();
  if (code >= 0) {
    int pos = code * CSTRIDE + lb[code] + lpos;
    float c2 = __fadd_rn(__fadd_rn(__fmul_rn(v.x,v.x), __fmul_rn(v.y,v.y)),
                         __fmul_rn(v.z,v.z));
    pC[pos] = make_float4(v.x, v.y, v.z, c2);
    pSlot[pos] = s;
  }
}

// ---------------- K3: probe targets + INLINE per-block fallback ------------------
// Misses are compacted per-block into LDS, bucketed by (batch,label) code, then
// scanned against the code's pure-cluster list with the exact legacy 16-lane-group
// LDS-tile kernel arithmetic (min over monotone-float-bits key | slot).
__global__ void __launch_bounds__(256) k_targets_fb(
    const float* __restrict__ grid, const int* __restrict__ label,
    const int* __restrict__ batch,
    const float4* __restrict__ ctr,
    const int* __restrict__ blCnt, const float* __restrict__ blSum,
    const float4* __restrict__ pC, const int* __restrict__ pSlot,
    const int* __restrict__ codeCnt,
    float* tgt, float* mag, int* ghist, int n) {
  __shared__ int h[HB];                       // 8 KB
  __shared__ float4 mpt[256];                 // miss point {gx,gy,gz,p2}  4 KB
  __shared__ int midx[256];                   // miss point index          1 KB
  __shared__ unsigned long long bestk[256];   // per-miss best key         2 KB
  __shared__ int cnt16[NCODE];
  __shared__ int mofs[NCODE];
  __shared__ float4 tile[1024];               // cluster tile             16 KB
  __shared__ int stile[1024];                 //                           4 KB

  int tid = threadIdx.x;
  for (int t = tid; t < HB; t += 256) h[t] = 0;
  if (tid < NCODE) cnt16[tid] = 0;
  __syncthreads();

  int i = blockIdx.x * blockDim.x + tid;
  bool miss = false;
  int mcode = -1;
  float gx = 0.f, gy = 0.f, gz = 0.f;

  // ---- phase A: probes (identical to legacy k_targets) ----
  if (i < n) {
    gx = grid[3*i]; gy = grid[3*i+1]; gz = grid[3*i+2];
    int vx = (int)floorf(gx * (1.0f/16.0f));
    int vy = (int)floorf(gy * (1.0f/16.0f));
    int vz = (int)floorf(gz * (1.0f/16.0f));
    int b = batch[i], l = label[i];
    int s = voxslot(b, vx, vy, vz);

    float4 own = ctr[s];
    bool purept = (__float_as_int(own.w) >= 0);

    int bl = b * NCLS + l;
    float fbc = (float)max(blCnt[bl], 1);
    float gcx = __fdiv_rn(blSum[3*bl],   fbc);
    float gcy = __fdiv_rn(blSum[3*bl+1], fbc);
    float gcz = __fdiv_rn(blSum[3*bl+2], fbc);

    float dx = __fsub_rn(gcx, own.x);
    float dy = __fsub_rn(gcy, own.y);
    float dz = __fsub_rn(gcz, own.z);
    int sgx = (dx > 0.f) ? 1 : ((dx < 0.f) ? -1 : 0);
    int sgy = (dy > 0.f) ? 1 : ((dy < 0.f) ? -1 : 0);
    int sgz = (dz > 0.f) ? 1 : ((dz < 0.f) ? -1 : 0);

    int ax1 = vx + sgx,     ay1 = vy + sgy,     az1 = vz + sgz;
    int ax2 = vx + 2 * sgx, ay2 = vy + 2 * sgy, az2 = vz + 2 * sgz;
    bool v1 = (unsigned)ax1 < (unsigned)VOXD && (unsigned)ay1 < (unsigned)VOXD &&
              (unsigned)az1 < (unsigned)VOXD;
    bool v2 = (unsigned)ax2 < (unsigned)VOXD && (unsigned)ay2 < (unsigned)VOXD &&
              (unsigned)az2 < (unsigned)VOXD;

    float4 q1 = make_float4(0.f, 0.f, 0.f, __int_as_float(-3));
    float4 q2 = q1;
    if (v1) q1 = ctr[voxslot(b, ax1, ay1, az1)];
    if (v2) q2 = ctr[voxslot(b, ax2, ay2, az2)];

    bool hit1 = v1 && (__float_as_int(q1.w) == l);
    bool hit2 = v2 && (__float_as_int(q2.w) == l);
    bool hit = hit1 || hit2;

    float tx = hit1 ? q1.x : (hit2 ? q2.x : gx);
    float ty = hit1 ? q1.y : (hit2 ? q2.y : gy);
    float tz = hit1 ? q1.z : (hit2 ? q2.z : gz);

    tgt[3*i] = tx; tgt[3*i+1] = ty; tgt[3*i+2] = tz;
    miss = (!purept && !hit);
    if (miss) {
      mcode = bl;
    } else {
      float tox = __fsub_rn(tx, gx), toy = __fsub_rn(ty, gy), toz = __fsub_rn(tz, gz);
      float ssq = __fadd_rn(__fadd_rn(__fmul_rn(tox,tox), __fmul_rn(toy,toy)),
                            __fmul_rn(toz,toz));
      float m = (ssq > 0.f) ? sqrtf(ssq) : 0.f;
      mag[i] = m;
      atomicAdd(&h[__float_as_uint(m) >> 21], 1);
    }
  }

  // ---- compact misses into LDS, bucketed by code ----
  int lpos = -1;
  if (miss) lpos = atomicAdd(&cnt16[mcode], 1);
  __syncthreads();
  if (tid == 0) {
    int acc = 0;
    #pragma unroll
    for (int c = 0; c < NCODE; ++c) { mofs[c] = acc; acc += cnt16[c]; }
  }
  __syncthreads();
  if (miss) {
    int pos = mofs[mcode] + lpos;
    midx[pos] = i;
    float p2 = __fadd_rn(__fadd_rn(__fmul_rn(gx,gx), __fmul_rn(gy,gy)),
                         __fmul_rn(gz,gz));
    mpt[pos] = make_float4(gx, gy, gz, p2);
  }
  __syncthreads();

  // ---- phase B: per-code fallback scans (legacy k_fallback arithmetic) ----
  int g = tid >> 4;          // 16 groups of 16 lanes
  int q = tid & (GSZ - 1);
  for (int c = 0; c < NCODE; ++c) {
    int mc = cnt16[c];
    if (mc == 0) continue;                    // block-uniform
    int cc = codeCnt[c];
    int j0 = c * CSTRIDE;
    int off = mofs[c];
    for (int t = tid; t < mc; t += 256) bestk[off + t] = 0xFFFFFFFFFFFFFFFFULL;
    __syncthreads();
    for (int tb = 0; tb < cc; tb += 1024) {
      int m = min(1024, cc - tb);
      for (int j = tid; j < m; j += 256) {
        tile[j] = pC[j0 + tb + j];
        stile[j] = pSlot[j0 + tb + j];
      }
      __syncthreads();
      for (int t = g; t < mc; t += GSZ) {
        float4 pp = mpt[off + t];
        unsigned long long key = 0xFFFFFFFFFFFFFFFFULL;
        #pragma unroll 4
        for (int j = q; j < m; j += GSZ) {
          float4 cl = tile[j];
          float dot = __fadd_rn(__fadd_rn(__fmul_rn(pp.x,cl.x), __fmul_rn(pp.y,cl.y)),
                                __fmul_rn(pp.z,cl.z));
          float d2 = __fadd_rn(__fsub_rn(pp.w, __fmul_rn(2.0f, dot)), cl.w);
          unsigned fb = __float_as_uint(d2);
          fb = (fb >> 31) ? ~fb : (fb | 0x80000000u);
          unsigned long long k2 = ((unsigned long long)fb << 32) | (unsigned)stile[j];
          if (k2 < key) key = k2;
        }
        #pragma unroll
        for (int o = 1; o < GSZ; o <<= 1) {
          unsigned long long ok = __shfl_xor(key, o, 64);
          if (ok < key) key = ok;
        }
        if (q == 0 && key < bestk[off + t]) bestk[off + t] = key;
      }
      __syncthreads();
    }
    // write results for this code's misses
    for (int t = tid; t < mc; t += 256) {
      unsigned long long key = bestk[off + t];
      int idx = midx[off + t];
      float4 pp = mpt[off + t];
      float mv = 0.f;
      if (cc > 0) {
        int slot = (int)(unsigned)(key & 0xFFFFFFFFULL);
        float4 cl = ctr[slot];
        tgt[3*idx] = cl.x; tgt[3*idx+1] = cl.y; tgt[3*idx+2] = cl.z;
        float tox = __fsub_rn(cl.x, pp.x), toy = __fsub_rn(cl.y, pp.y),
              toz = __fsub_rn(cl.z, pp.z);
        float ssq = __fadd_rn(__fadd_rn(__fmul_rn(tox,tox), __fmul_rn(toy,toy)),
                              __fmul_rn(toz,toz));
        mv = (ssq > 0.f) ? sqrtf(ssq) : 0.f;
      }
      mag[idx] = mv;
      atomicAdd(&h[__float_as_uint(mv) >> 21], 1);
    }
    __syncthreads();
  }

  // ---- flush histogram ----
  for (int t = tid; t < HB; t += 256) {
    int cv = h[t];
    if (cv != 0) atomicAdd(&ghist[t], cv);
  }
}

// ---------------- K4: redundant exact quantile select + loss ---------------------
// Every block independently derives the exact threshold from ghist + two radix
// passes over mag (identical arithmetic to legacy k_gather/k_sel), then runs the
// legacy k_loss body with the locally-computed threshold. No inter-block comms
// before the final done-counter reduction.
__global__ void __launch_bounds__(256) k_loss_sel(
    const float* __restrict__ pred, const float* __restrict__ grid,
    const float* __restrict__ tgt, const float* __restrict__ mag,
    const int* __restrict__ ghist, Scalars* sc, float* out,
    int n, int r0, int r1, double tfrac) {
  __shared__ int histA[HB];     // 8 KB
  __shared__ int histB[HB];     // 8 KB
  __shared__ int ws[4];
  __shared__ int s_misc[8];
  __shared__ double shH[256];
  __shared__ double shC[256];
  __shared__ int shN[256];
  __shared__ int shM[256];
  int tid = threadIdx.x;

  // ---- step 1: coarse bins from ghist (legacy k_gather logic) ----
  int base8 = tid * 8;
  int cbin[8];
  int s = 0;
  #pragma unroll
  for (int k = 0; k < 8; ++k) { cbin[k] = ghist[base8 + k]; s += cbin[k]; }
  int incl = block_scan256(s, ws);
  int lo = incl - s;
  if (r0 >= lo && r0 < lo + s) {
    int acc = lo;
    #pragma unroll
    for (int k = 0; k < 8; ++k) {
      if (r0 < acc + cbin[k]) { s_misc[0] = base8 + k; s_misc[1] = r0 - acc; break; }
      acc += cbin[k];
    }
  }
  if (r1 >= lo && r1 < lo + s) {
    int acc = lo;
    #pragma unroll
    for (int k = 0; k < 8; ++k) {
      if (r1 < acc + cbin[k]) { s_misc[2] = base8 + k; s_misc[3] = r1 - acc; break; }
      acc += cbin[k];
    }
  }
  __syncthreads();
  int binA = s_misc[0], rA = s_misc[1], binB = s_misc[2], rB = s_misc[3];

  // ---- step 2: mid-bits histograms (pass 1 over mag) ----
  for (int t = tid; t < HB; t += 256) { histA[t] = 0; histB[t] = 0; }
  __syncthreads();
  {
    const uint4* m4 = (const uint4*)mag;
    int nv = n >> 2;
    for (int v = tid; v < nv; v += 256) {
      uint4 u = m4[v];
      unsigned b0 = u.x, b1 = u.y, b2 = u.z, b3 = u.w;
      if ((b0 >> 21) == (unsigned)binA) atomicAdd(&histA[(b0 >> 10) & 0x7FF], 1);
      if ((b0 >> 21) == (unsigned)binB) atomicAdd(&histB[(b0 >> 10) & 0x7FF], 1);
      if ((b1 >> 21) == (unsigned)binA) atomicAdd(&histA[(b1 >> 10) & 0x7FF], 1);
      if ((b1 >> 21) == (unsigned)binB) atomicAdd(&histB[(b1 >> 10) & 0x7FF], 1);
      if ((b2 >> 21) == (unsigned)binA) atomicAdd(&histA[(b2 >> 10) & 0x7FF], 1);
      if ((b2 >> 21) == (unsigned)binB) atomicAdd(&histB[(b2 >> 10) & 0x7FF], 1);
      if ((b3 >> 21) == (unsigned)binA) atomicAdd(&histA[(b3 >> 10) & 0x7FF], 1);
      if ((b3 >> 21) == (unsigned)binB) atomicAdd(&histB[(b3 >> 10) & 0x7FF], 1);
    }
    for (int t = (nv << 2) + tid; t < n; t += 256) {
      unsigned b0 = __float_as_uint(mag[t]);
      if ((b0 >> 21) == (unsigned)binA) atomicAdd(&histA[(b0 >> 10) & 0x7FF], 1);
      if ((b0 >> 21) == (unsigned)binB) atomicAdd(&histB[(b0 >> 10) & 0x7FF], 1);
    }
  }
  __syncthreads();

  // ---- step 3: scan mid histograms ----
  {
    int a8[8], sA = 0;
    #pragma unroll
    for (int k = 0; k < 8; ++k) { a8[k] = histA[base8 + k]; sA += a8[k]; }
    int inclA = block_scan256(sA, ws);
    int accA = inclA - sA;
    #pragma unroll
    for (int k = 0; k < 8; ++k) {
      if (rA >= accA && rA < accA + a8[k]) { s_misc[4] = base8 + k; s_misc[5] = rA - accA; }
      accA += a8[k];
    }
    int b8[8], sB = 0;
    #pragma unroll
    for (int k = 0; k < 8; ++k) { b8[k] = histB[base8 + k]; sB += b8[k]; }
    int inclB = block_scan256(sB, ws);
    int accB = inclB - sB;
    #pragma unroll
    for (int k = 0; k < 8; ++k) {
      if (rB >= accB && rB < accB + b8[k]) { s_misc[6] = base8 + k; s_misc[7] = rB - accB; }
      accB += b8[k];
    }
  }
  __syncthreads();
  int subA = s_misc[4], subRA = s_misc[5], subB = s_misc[6], subRB = s_misc[7];

  // ---- step 4: low-bits histograms (pass 2 over mag) ----
  for (int t = tid; t < 1024; t += 256) { histA[t] = 0; histB[t] = 0; }
  __syncthreads();
  {
    const uint4* m4 = (const uint4*)mag;
    int nv = n >> 2;
    for (int v = tid; v < nv; v += 256) {
      uint4 u = m4[v];
      unsigned bb[4] = { u.x, u.y, u.z, u.w };
      #pragma unroll
      for (int k = 0; k < 4; ++k) {
        unsigned b0 = bb[k];
        if ((b0 >> 21) == (unsigned)binA && (int)((b0 >> 10) & 0x7FF) == subA)
          atomicAdd(&histA[b0 & 0x3FF], 1);
        if ((b0 >> 21) == (unsigned)binB && (int)((b0 >> 10) & 0x7FF) == subB)
          atomicAdd(&histB[b0 & 0x3FF], 1);
      }
    }
    for (int t = (nv << 2) + tid; t < n; t += 256) {
      unsigned b0 = __float_as_uint(mag[t]);
      if ((b0 >> 21) == (unsigned)binA && (int)((b0 >> 10) & 0x7FF) == subA)
        atomicAdd(&histA[b0 & 0x3FF], 1);
      if ((b0 >> 21) == (unsigned)binB && (int)((b0 >> 10) & 0x7FF) == subB)
        atomicAdd(&histB[b0 & 0x3FF], 1);
    }
  }
  __syncthreads();

  // ---- step 5: scan low histograms ----
  {
    int base4 = tid * 4;
    int la[4], sA = 0;
    #pragma unroll
    for (int k = 0; k < 4; ++k) { la[k] = histA[base4 + k]; sA += la[k]; }
    int inclA = block_scan256(sA, ws);
    int accA = inclA - sA;
    #pragma unroll
    for (int k = 0; k < 4; ++k) {
      if (subRA >= accA && subRA < accA + la[k]) s_misc[0] = base4 + k;
      accA += la[k];
    }
    int lb4[4], sB = 0;
    #pragma unroll
    for (int k = 0; k < 4; ++k) { lb4[k] = histB[base4 + k]; sB += lb4[k]; }
    int inclB = block_scan256(sB, ws);
    int accB = inclB - sB;
    #pragma unroll
    for (int k = 0; k < 4; ++k) {
      if (subRB >= accB && subRB < accB + lb4[k]) s_misc[1] = base4 + k;
      accB += lb4[k];
    }
  }
  __syncthreads();
  unsigned va = ((unsigned)binA << 21) | ((unsigned)subA << 10) | (unsigned)s_misc[0];
  unsigned vb = ((unsigned)binB << 21) | ((unsigned)subB << 10) | (unsigned)s_misc[1];
  float th;
  {
    double a = (double)__uint_as_float(va);
    double b = (double)__uint_as_float(vb);
    double thd = (tfrac >= 0.5) ? (b - (b - a) * (1.0 - tfrac)) : (a + (b - a) * tfrac);
    th = (float)thd;
  }
  __syncthreads();

  // ---- step 6: loss (legacy k_loss body) ----
  int i = blockIdx.x * blockDim.x + tid;
  double hub = 0.0, cs = 0.0;
  int c1 = 0, cmd = 0;
  if (i < n) {
    float m = mag[i];
    if (m <= th) {
      c1 = 1;
      float tox = __fsub_rn(tgt[3*i],   grid[3*i]);
      float toy = __fsub_rn(tgt[3*i+1], grid[3*i+1]);
      float toz = __fsub_rn(tgt[3*i+2], grid[3*i+2]);
      float px = pred[3*i], py = pred[3*i+1], pz = pred[3*i+2];
      float d0 = __fsub_rn(px, tox), d1 = __fsub_rn(py, toy), d2 = __fsub_rn(pz, toz);
      float a0 = fabsf(d0), a1 = fabsf(d1), a2 = fabsf(d2);
      float h0 = (a0 < 1.f) ? __fmul_rn(__fmul_rn(0.5f, d0), d0) : __fsub_rn(a0, 0.5f);
      float h1 = (a1 < 1.f) ? __fmul_rn(__fmul_rn(0.5f, d1), d1) : __fsub_rn(a1, 0.5f);
      float h2 = (a2 < 1.f) ? __fmul_rn(__fmul_rn(0.5f, d2), d2) : __fsub_rn(a2, 0.5f);
      hub = (double)h0 + (double)h1 + (double)h2;
      if (m > 0.f) {
        cmd = 1;
        float ps = __fadd_rn(__fadd_rn(__fmul_rn(px,px), __fmul_rn(py,py)), __fmul_rn(pz,pz));
        float pn = (ps > 0.f) ? sqrtf(ps) : 0.f;
        float dotp = __fadd_rn(__fadd_rn(__fmul_rn(px,tox), __fmul_rn(py,toy)),
                               __fmul_rn(pz,toz));
        float den = fmaxf(__fmul_rn(pn, m), 1e-4f);
        cs = (double)__fdiv_rn(dotp, den);
      }
    }
  }
  shH[tid] = hub; shC[tid] = cs; shN[tid] = c1; shM[tid] = cmd;
  __syncthreads();
  for (int off = 128; off > 0; off >>= 1) {
    if (tid < off) {
      shH[tid] += shH[tid+off];
      shC[tid] += shC[tid+off];
      shN[tid] += shN[tid+off];
      shM[tid] += shM[tid+off];
    }
    __syncthreads();
  }
  if (tid == 0) {
    atomicAdd(&sc->hub, shH[0]);
    atomicAdd(&sc->cosSum, shC[0]);
    atomicAdd(&sc->n1, shN[0]);
    atomicAdd(&sc->nmd, shM[0]);
    __threadfence();
    int d = atomicAdd(&sc->done, 1);
    if (d == (int)gridDim.x - 1) {
      __threadfence();
      double th_hub = atomicAdd(&sc->hub, 0.0);
      double th_cos = atomicAdd(&sc->cosSum, 0.0);
      int n1 = atomicAdd(&sc->n1, 0);
      int nmd = atomicAdd(&sc->nmd, 0);
      double l1 = (n1 > 0) ? th_hub / fmax((double)n1 * 3.0, 1.0) : 0.0;
      double ld = (nmd > 0) ? (1.0 - th_cos / fmax((double)nmd, 1.0)) : 0.0;
      out[0] = (float)l1;
      out[1] = (float)ld;
    }
  }
}

extern "C" void kernel_launch(void* const* d_in, const int* in_sizes, int n_in,
                              void* d_out, int out_size, void* d_ws, size_t ws_size,
                              hipStream_t stream) {
  const float* pred  = (const float*)d_in[0];
  const float* grid  = (const float*)d_in[1];
  const int*   label = (const int*)d_in[2];
  const int*   batch = (const int*)d_in[3];
  int n = in_sizes[2];

  char* p = (char*)d_ws;
  auto take = [&](size_t bytes) -> char* {
    char* r = p;
    p += (bytes + 255) & ~(size_t)255;
    return r;
  };
  // ---- zero-init region (one hipMemsetAsync covers all of it) ----
  char* zbase = p;
  unsigned long long* vA = (unsigned long long*)take((size_t)SLOTS*8);
  unsigned long long* vB = (unsigned long long*)take((size_t)SLOTS*8);
  int*    lmask    = (int*)   take((size_t)SLOTS*4);
  int*    codeCnt  = (int*)   take(NCODE*4);
  int*    blCnt    = (int*)   take(16*4);
  float*  blSum    = (float*) take(48*4);
  int*    ghist    = (int*)   take((size_t)HB*4);
  Scalars* sc      = (Scalars*)take(sizeof(Scalars));
  size_t zbytes = (size_t)(p - zbase);
  // ---- uninitialized buffers ----
  float4* ctr      = (float4*)take((size_t)SLOTS*16);
  float4* pC       = (float4*)take((size_t)NCODE*CSTRIDE*16);
  int*    pSlot    = (int*)   take((size_t)NCODE*CSTRIDE*4);
  float*  tgt      = (float*) take((size_t)n*3*4);
  float*  mag      = (float*) take((size_t)n*4);

  int nb = (n + 255) / 256;

  double vi = 0.99 * (double)(n - 1);
  int r0 = (int)vi;
  int r1 = r0 + 1; if (r1 > n - 1) r1 = n - 1;
  double tfrac = vi - (double)r0;

  hipMemsetAsync(zbase, 0, zbytes, stream);
  k_scatter<<<nb, 256, 0, stream>>>(grid, label, batch, vA, vB, lmask,
                                    blCnt, blSum, n);
  k_prep<<<NBLK, 256, 0, stream>>>(vA, vB, lmask, ctr, pC, pSlot, codeCnt);
  k_targets_fb<<<nb, 256, 0, stream>>>(grid, label, batch, ctr, blCnt, blSum,
                                       pC, pSlot, codeCnt, tgt, mag, ghist, n);
  k_loss_sel<<<nb, 256, 0, stream>>>(pred, grid, tgt, mag, ghist, sc,
                                     (float*)d_out, n, r0, r1, tfrac);
}

// Round 3
// 198.817 us; speedup vs baseline: 3.4668x; 1.1131x over previous
//
#include <hip/hip_runtime.h>
#include <climits>

#define VOXD 25
#define SLOT3 (VOXD*VOXD*VOXD)      // 15625
#define SLOTS (2*SLOT3)             // 31250
#define NCLS 8
#define NCODE 16
#define NBLK ((SLOTS + 255) / 256)  // 123
#define HB 2048                     // radix bins (11 bits)
#define GSZ 16                      // threads per miss point in fallback
#define PPB 64                      // points per block in k_targets_fb
#define CSTRIDE SLOT3               // per-code bucket capacity

struct Scalars {
  double hub;
  double cosSum;
  int n1;
  int nmd;
  float thresh;
  int done;    // k_targets_fb finalize counter
  int done2;   // k_loss finalize counter
};

__device__ __forceinline__ int voxslot(int b, int vx, int vy, int vz) {
  return ((b * VOXD + vx) * VOXD + vy) * VOXD + vz;
}

// 256-thread (4-wave) inclusive block scan; ws[4] shared scratch.
// Trailing barrier makes ws immediately reusable by the next call.
__device__ __forceinline__ int block_scan256(int v, int* ws) {
  int lane = threadIdx.x & 63, w = threadIdx.x >> 6;
  int s = v;
  #pragma unroll
  for (int off = 1; off < 64; off <<= 1) {
    int t = __shfl_up(s, off, 64);
    if (lane >= off) s += t;
  }
  if (lane == 63) ws[w] = s;
  __syncthreads();
  int add = 0;
  #pragma unroll
  for (int q = 0; q < 4; ++q) if (q < w) add += ws[q];
  __syncthreads();
  return s + add;
}

// ---------------- K1: scatter with packed integer-exact atomics ------------------
__global__ void k_scatter(const float* __restrict__ grid, const int* __restrict__ label,
                          const int* __restrict__ batch,
                          unsigned long long* vA, unsigned long long* vB, int* lmask,
                          int* blCnt, float* blSum, int n) {
  __shared__ int sCnt[NCODE];
  __shared__ float sSum[3 * NCODE];
  int tid = threadIdx.x;
  if (tid < NCODE) sCnt[tid] = 0;
  if (tid < 3 * NCODE) sSum[tid] = 0.f;
  __syncthreads();
  int i = blockIdx.x * blockDim.x + tid;
  if (i < n) {
    float gx = grid[3*i], gy = grid[3*i+1], gz = grid[3*i+2];
    int ix = (int)gx, iy = (int)gy, iz = (int)gz;   // coords are exact small ints
    int vx = (int)floorf(gx * (1.0f/16.0f));
    int vy = (int)floorf(gy * (1.0f/16.0f));
    int vz = (int)floorf(gz * (1.0f/16.0f));
    int b = batch[i], l = label[i];
    int s = voxslot(b, vx, vy, vz);
    atomicAdd(&vA[s], ((unsigned long long)(unsigned)ix << 32) | (unsigned)iy);
    atomicAdd(&vB[s], ((unsigned long long)(unsigned)iz << 24) | 1ULL);
    atomicOr(&lmask[s], 1 << l);
    int bl = b * NCLS + l;
    atomicAdd(&sCnt[bl], 1);
    atomicAdd(&sSum[3*bl], gx); atomicAdd(&sSum[3*bl+1], gy); atomicAdd(&sSum[3*bl+2], gz);
  }
  __syncthreads();
  if (tid < NCODE && sCnt[tid] != 0) atomicAdd(&blCnt[tid], sCnt[tid]);
  if (tid < 3 * NCODE && sSum[tid] != 0.f) atomicAdd(&blSum[tid], sSum[tid]);
}

// ---------------- K2: decode tables -> slot float4 + per-code bucket append ------
// pC.w packs the slot id (bit container); c2 is recomputed bit-identically in the
// fallback loop, halving the fallback stream.
__global__ void k_prep(const unsigned long long* vA, const unsigned long long* vB,
                       const int* lmask, float4* ctr, float4* pC, int* codeCnt) {
  __shared__ int lc[NCODE];
  __shared__ int lb[NCODE];
  int tid = threadIdx.x;
  if (tid < NCODE) lc[tid] = 0;
  __syncthreads();
  int s = blockIdx.x * 256 + tid;
  int code = -1, lpos = 0;
  float4 v = make_float4(0.f, 0.f, 0.f, __int_as_float(-2));
  if (s < SLOTS) {
    unsigned long long bq = vB[s];
    unsigned c = (unsigned)(bq & 0xFFFFFFULL);
    if (c > 0) {
      unsigned long long aq = vA[s];
      float fc = (float)c;
      float cx = __fdiv_rn((float)(unsigned)(aq >> 32), fc);
      float cy = __fdiv_rn((float)(unsigned)(aq & 0xFFFFFFFFULL), fc);
      float cz = __fdiv_rn((float)(unsigned)(bq >> 24), fc);
      int m = lmask[s];
      bool pure = (m & (m - 1)) == 0;
      int lbl = __ffs(m) - 1;
      v = make_float4(cx, cy, cz, __int_as_float(pure ? lbl : -1));
      if (pure) {
        code = (s / SLOT3) * NCLS + lbl;
        lpos = atomicAdd(&lc[code], 1);
      }
    }
    ctr[s] = v;
  }
  __syncthreads();
  if (tid < NCODE) lb[tid] = (lc[tid] > 0) ? atomicAdd(&codeCnt[tid], lc[tid]) : 0;
  __syncthreads();
  if (code >= 0) {
    int pos = code * CSTRIDE + lb[code] + lpos;
    pC[pos] = make_float4(v.x, v.y, v.z, __int_as_float(s));
  }
}

// ---------------- K3: probes + barrier-free streaming fallback + finalize --------
// 64 points/block -> grid ~1024 (4 blocks/CU, 16 waves/CU). Misses compact to LDS;
// 16-lane groups stream their code's L2-resident cluster list directly (no LDS
// tiles, no barriers in the scan). Last block (done-counter) runs the exact
// quantile select (round-2-verified radix arithmetic) and writes sc->thresh.
__global__ void __launch_bounds__(256) k_targets_fb(
    const float* __restrict__ grid, const int* __restrict__ label,
    const int* __restrict__ batch,
    const float4* __restrict__ ctr,
    const int* __restrict__ blCnt, const float* __restrict__ blSum,
    const float4* __restrict__ pC, const int* __restrict__ codeCnt,
    float* tgt, float* mag, int* ghist, Scalars* sc,
    int n, int nblocks, int r0, int r1, double tfrac) {
  __shared__ int h[HB];          // phase hist; reused as histA in finalize (8 KB)
  __shared__ int h2[HB];         // finalize histB (8 KB)
  __shared__ float4 mpt[PPB];    // miss {gx,gy,gz,p2}
  __shared__ int midx[PPB];
  __shared__ int mcd[PPB];
  __shared__ int mcnt;
  __shared__ int ws[4];
  __shared__ int s_misc[8];
  __shared__ int sLast;

  int tid = threadIdx.x;
  for (int t = tid; t < HB; t += 256) h[t] = 0;
  if (tid == 0) mcnt = 0;
  __syncthreads();

  // ---- phase A: probes (wave 0 only; 64 points) ----
  int i = blockIdx.x * PPB + tid;
  if (tid < PPB && i < n) {
    float gx = grid[3*i], gy = grid[3*i+1], gz = grid[3*i+2];
    int vx = (int)floorf(gx * (1.0f/16.0f));
    int vy = (int)floorf(gy * (1.0f/16.0f));
    int vz = (int)floorf(gz * (1.0f/16.0f));
    int b = batch[i], l = label[i];
    int s = voxslot(b, vx, vy, vz);

    float4 own = ctr[s];
    bool purept = (__float_as_int(own.w) >= 0);

    int bl = b * NCLS + l;
    float fbc = (float)max(blCnt[bl], 1);
    float gcx = __fdiv_rn(blSum[3*bl],   fbc);
    float gcy = __fdiv_rn(blSum[3*bl+1], fbc);
    float gcz = __fdiv_rn(blSum[3*bl+2], fbc);

    float dx = __fsub_rn(gcx, own.x);
    float dy = __fsub_rn(gcy, own.y);
    float dz = __fsub_rn(gcz, own.z);
    int sgx = (dx > 0.f) ? 1 : ((dx < 0.f) ? -1 : 0);
    int sgy = (dy > 0.f) ? 1 : ((dy < 0.f) ? -1 : 0);
    int sgz = (dz > 0.f) ? 1 : ((dz < 0.f) ? -1 : 0);

    int ax1 = vx + sgx,     ay1 = vy + sgy,     az1 = vz + sgz;
    int ax2 = vx + 2 * sgx, ay2 = vy + 2 * sgy, az2 = vz + 2 * sgz;
    bool v1 = (unsigned)ax1 < (unsigned)VOXD && (unsigned)ay1 < (unsigned)VOXD &&
              (unsigned)az1 < (unsigned)VOXD;
    bool v2 = (unsigned)ax2 < (unsigned)VOXD && (unsigned)ay2 < (unsigned)VOXD &&
              (unsigned)az2 < (unsigned)VOXD;

    float4 q1 = make_float4(0.f, 0.f, 0.f, __int_as_float(-3));
    float4 q2 = q1;
    if (v1) q1 = ctr[voxslot(b, ax1, ay1, az1)];
    if (v2) q2 = ctr[voxslot(b, ax2, ay2, az2)];

    bool hit1 = v1 && (__float_as_int(q1.w) == l);
    bool hit2 = v2 && (__float_as_int(q2.w) == l);
    bool hit = hit1 || hit2;

    float tx = hit1 ? q1.x : (hit2 ? q2.x : gx);
    float ty = hit1 ? q1.y : (hit2 ? q2.y : gy);
    float tz = hit1 ? q1.z : (hit2 ? q2.z : gz);

    tgt[3*i] = tx; tgt[3*i+1] = ty; tgt[3*i+2] = tz;
    bool miss = (!purept && !hit);
    if (miss) {
      int p = atomicAdd(&mcnt, 1);
      midx[p] = i;
      mcd[p] = bl;
      float p2 = __fadd_rn(__fadd_rn(__fmul_rn(gx,gx), __fmul_rn(gy,gy)),
                           __fmul_rn(gz,gz));
      mpt[p] = make_float4(gx, gy, gz, p2);
    } else {
      float tox = __fsub_rn(tx, gx), toy = __fsub_rn(ty, gy), toz = __fsub_rn(tz, gz);
      float ssq = __fadd_rn(__fadd_rn(__fmul_rn(tox,tox), __fmul_rn(toy,toy)),
                            __fmul_rn(toz,toz));
      float m = (ssq > 0.f) ? sqrtf(ssq) : 0.f;
      mag[i] = m;
      atomicAdd(&h[__float_as_uint(m) >> 21], 1);
    }
  }
  __syncthreads();

  // ---- phase B: barrier-free streaming fallback (16 groups x 16 lanes) ----
  int nm = mcnt;
  int g = tid >> 4;
  int q = tid & (GSZ - 1);
  for (int t = g; t < nm; t += 16) {
    float4 pp = mpt[t];
    int c = mcd[t];
    int cc = codeCnt[c];
    int j0 = c * CSTRIDE;
    unsigned long long key = 0xFFFFFFFFFFFFFFFFULL;
    #pragma unroll 4
    for (int j = q; j < cc; j += GSZ) {
      float4 cl = pC[j0 + j];
      float c2 = __fadd_rn(__fadd_rn(__fmul_rn(cl.x,cl.x), __fmul_rn(cl.y,cl.y)),
                           __fmul_rn(cl.z,cl.z));
      float dot = __fadd_rn(__fadd_rn(__fmul_rn(pp.x,cl.x), __fmul_rn(pp.y,cl.y)),
                            __fmul_rn(pp.z,cl.z));
      float d2 = __fadd_rn(__fsub_rn(pp.w, __fmul_rn(2.0f, dot)), c2);
      unsigned fb = __float_as_uint(d2);
      fb = (fb >> 31) ? ~fb : (fb | 0x80000000u);
      unsigned long long k2 = ((unsigned long long)fb << 32) |
                              (unsigned)__float_as_int(cl.w);
      if (k2 < key) key = k2;
    }
    #pragma unroll
    for (int o = 1; o < GSZ; o <<= 1) {
      unsigned long long ok = __shfl_xor(key, o, 64);
      if (ok < key) key = ok;
    }
    if (q == 0) {
      int idx = midx[t];
      float mv = 0.f;
      if (cc > 0) {
        int slot = (int)(unsigned)(key & 0xFFFFFFFFULL);
        float4 cl = ctr[slot];
        tgt[3*idx] = cl.x; tgt[3*idx+1] = cl.y; tgt[3*idx+2] = cl.z;
        float tox = __fsub_rn(cl.x, pp.x), toy = __fsub_rn(cl.y, pp.y),
              toz = __fsub_rn(cl.z, pp.z);
        float ssq = __fadd_rn(__fadd_rn(__fmul_rn(tox,tox), __fmul_rn(toy,toy)),
                              __fmul_rn(toz,toz));
        mv = (ssq > 0.f) ? sqrtf(ssq) : 0.f;
      }
      mag[idx] = mv;
      atomicAdd(&h[__float_as_uint(mv) >> 21], 1);
    }
  }
  __syncthreads();

  // ---- flush histogram ----
  for (int t = tid; t < HB; t += 256) {
    int cv = h[t];
    if (cv != 0) atomicAdd(&ghist[t], cv);
  }
  __syncthreads();

  // ---- done-counter; last block runs exact quantile select ----
  if (tid == 0) {
    __threadfence();
    int d = atomicAdd(&sc->done, 1);
    sLast = (d == nblocks - 1) ? 1 : 0;
  }
  __syncthreads();
  if (!sLast) return;
  __threadfence();   // acquire: other blocks' mag stores + ghist atomics

  // ---- finalize: exact 99th percentile (round-2-verified radix select) ----
  // step 1: coarse bins from ghist
  int base8 = tid * 8;
  {
    int cbin[8];
    int s = 0;
    #pragma unroll
    for (int k = 0; k < 8; ++k) { cbin[k] = ghist[base8 + k]; s += cbin[k]; }
    int incl = block_scan256(s, ws);
    int lo = incl - s;
    if (r0 >= lo && r0 < lo + s) {
      int acc = lo;
      #pragma unroll
      for (int k = 0; k < 8; ++k) {
        if (r0 < acc + cbin[k]) { s_misc[0] = base8 + k; s_misc[1] = r0 - acc; break; }
        acc += cbin[k];
      }
    }
    if (r1 >= lo && r1 < lo + s) {
      int acc = lo;
      #pragma unroll
      for (int k = 0; k < 8; ++k) {
        if (r1 < acc + cbin[k]) { s_misc[2] = base8 + k; s_misc[3] = r1 - acc; break; }
        acc += cbin[k];
      }
    }
  }
  __syncthreads();
  int binA = s_misc[0], rA = s_misc[1], binB = s_misc[2], rB = s_misc[3];

  // step 2: mid-bits histograms (pass 1 over mag)
  for (int t = tid; t < HB; t += 256) { h[t] = 0; h2[t] = 0; }
  __syncthreads();
  {
    const uint4* m4 = (const uint4*)mag;
    int nv = n >> 2;
    for (int v = tid; v < nv; v += 256) {
      uint4 u = m4[v];
      unsigned bb[4] = { u.x, u.y, u.z, u.w };
      #pragma unroll
      for (int k = 0; k < 4; ++k) {
        unsigned b0 = bb[k];
        if ((b0 >> 21) == (unsigned)binA) atomicAdd(&h[(b0 >> 10) & 0x7FF], 1);
        if ((b0 >> 21) == (unsigned)binB) atomicAdd(&h2[(b0 >> 10) & 0x7FF], 1);
      }
    }
    for (int t = (nv << 2) + tid; t < n; t += 256) {
      unsigned b0 = __float_as_uint(mag[t]);
      if ((b0 >> 21) == (unsigned)binA) atomicAdd(&h[(b0 >> 10) & 0x7FF], 1);
      if ((b0 >> 21) == (unsigned)binB) atomicAdd(&h2[(b0 >> 10) & 0x7FF], 1);
    }
  }
  __syncthreads();

  // step 3: scan mid histograms
  {
    int a8[8], sA = 0;
    #pragma unroll
    for (int k = 0; k < 8; ++k) { a8[k] = h[base8 + k]; sA += a8[k]; }
    int inclA = block_scan256(sA, ws);
    int accA = inclA - sA;
    #pragma unroll
    for (int k = 0; k < 8; ++k) {
      if (rA >= accA && rA < accA + a8[k]) { s_misc[4] = base8 + k; s_misc[5] = rA - accA; }
      accA += a8[k];
    }
    int b8[8], sB = 0;
    #pragma unroll
    for (int k = 0; k < 8; ++k) { b8[k] = h2[base8 + k]; sB += b8[k]; }
    int inclB = block_scan256(sB, ws);
    int accB = inclB - sB;
    #pragma unroll
    for (int k = 0; k < 8; ++k) {
      if (rB >= accB && rB < accB + b8[k]) { s_misc[6] = base8 + k; s_misc[7] = rB - accB; }
      accB += b8[k];
    }
  }
  __syncthreads();
  int subA = s_misc[4], subRA = s_misc[5], subB = s_misc[6], subRB = s_misc[7];

  // step 4: low-bits histograms (pass 2 over mag)
  for (int t = tid; t < 1024; t += 256) { h[t] = 0; h2[t] = 0; }
  __syncthreads();
  {
    const uint4* m4 = (const uint4*)mag;
    int nv = n >> 2;
    for (int v = tid; v < nv; v += 256) {
      uint4 u = m4[v];
      unsigned bb[4] = { u.x, u.y, u.z, u.w };
      #pragma unroll
      for (int k = 0; k < 4; ++k) {
        unsigned b0 = bb[k];
        if ((b0 >> 21) == (unsigned)binA && (int)((b0 >> 10) & 0x7FF) == subA)
          atomicAdd(&h[b0 & 0x3FF], 1);
        if ((b0 >> 21) == (unsigned)binB && (int)((b0 >> 10) & 0x7FF) == subB)
          atomicAdd(&h2[b0 & 0x3FF], 1);
      }
    }
    for (int t = (nv << 2) + tid; t < n; t += 256) {
      unsigned b0 = __float_as_uint(mag[t]);
      if ((b0 >> 21) == (unsigned)binA && (int)((b0 >> 10) & 0x7FF) == subA)
        atomicAdd(&h[b0 & 0x3FF], 1);
      if ((b0 >> 21) == (unsigned)binB && (int)((b0 >> 10) & 0x7FF) == subB)
        atomicAdd(&h2[b0 & 0x3FF], 1);
    }
  }
  __syncthreads();

  // step 5: scan low histograms
  {
    int base4 = tid * 4;
    int la[4], sA = 0;
    #pragma unroll
    for (int k = 0; k < 4; ++k) { la[k] = h[base4 + k]; sA += la[k]; }
    int inclA = block_scan256(sA, ws);
    int accA = inclA - sA;
    #pragma unroll
    for (int k = 0; k < 4; ++k) {
      if (subRA >= accA && subRA < accA + la[k]) s_misc[0] = base4 + k;
      accA += la[k];
    }
    int lb4[4], sB = 0;
    #pragma unroll
    for (int k = 0; k < 4; ++k) { lb4[k] = h2[base4 + k]; sB += lb4[k]; }
    int inclB = block_scan256(sB, ws);
    int accB = inclB - sB;
    #pragma unroll
    for (int k = 0; k < 4; ++k) {
      if (subRB >= accB && subRB < accB + lb4[k]) s_misc[1] = base4 + k;
      accB += lb4[k];
    }
  }
  __syncthreads();
  if (tid == 0) {
    unsigned va = ((unsigned)binA << 21) | ((unsigned)subA << 10) | (unsigned)s_misc[0];
    unsigned vb = ((unsigned)binB << 21) | ((unsigned)subB << 10) | (unsigned)s_misc[1];
    double a = (double)__uint_as_float(va);
    double b = (double)__uint_as_float(vb);
    double th = (tfrac >= 0.5) ? (b - (b - a) * (1.0 - tfrac)) : (a + (b - a) * tfrac);
    sc->thresh = (float)th;
  }
}

// ---------------- K4: masked huber + cosine reductions + last-block finalize -----
__global__ void k_loss(const float* __restrict__ pred, const float* __restrict__ grid,
                       const float* __restrict__ tgt, const float* __restrict__ mag,
                       Scalars* sc, float* out, int n) {
  __shared__ double shH[256];
  __shared__ double shC[256];
  __shared__ int shN[256];
  __shared__ int shM[256];
  int tid = threadIdx.x;
  int i = blockIdx.x * blockDim.x + tid;
  double hub = 0.0, cs = 0.0;
  int c1 = 0, cmd = 0;
  if (i < n) {
    float th = sc->thresh;
    float m = mag[i];
    if (m <= th) {
      c1 = 1;
      float tox = __fsub_rn(tgt[3*i],   grid[3*i]);
      float toy = __fsub_rn(tgt[3*i+1], grid[3*i+1]);
      float toz = __fsub_rn(tgt[3*i+2], grid[3*i+2]);
      float px = pred[3*i], py = pred[3*i+1], pz = pred[3*i+2];
      float d0 = __fsub_rn(px, tox), d1 = __fsub_rn(py, toy), d2 = __fsub_rn(pz, toz);
      float a0 = fabsf(d0), a1 = fabsf(d1), a2 = fabsf(d2);
      float h0 = (a0 < 1.f) ? __fmul_rn(__fmul_rn(0.5f, d0), d0) : __fsub_rn(a0, 0.5f);
      float h1 = (a1 < 1.f) ? __fmul_rn(__fmul_rn(0.5f, d1), d1) : __fsub_rn(a1, 0.5f);
      float h2 = (a2 < 1.f) ? __fmul_rn(__fmul_rn(0.5f, d2), d2) : __fsub_rn(a2, 0.5f);
      hub = (double)h0 + (double)h1 + (double)h2;
      if (m > 0.f) {
        cmd = 1;
        float ps = __fadd_rn(__fadd_rn(__fmul_rn(px,px), __fmul_rn(py,py)), __fmul_rn(pz,pz));
        float pn = (ps > 0.f) ? sqrtf(ps) : 0.f;
        float dotp = __fadd_rn(__fadd_rn(__fmul_rn(px,tox), __fmul_rn(py,toy)),
                               __fmul_rn(pz,toz));
        float den = fmaxf(__fmul_rn(pn, m), 1e-4f);
        cs = (double)__fdiv_rn(dotp, den);
      }
    }
  }
  shH[tid] = hub; shC[tid] = cs; shN[tid] = c1; shM[tid] = cmd;
  __syncthreads();
  for (int off = 128; off > 0; off >>= 1) {
    if (tid < off) {
      shH[tid] += shH[tid+off];
      shC[tid] += shC[tid+off];
      shN[tid] += shN[tid+off];
      shM[tid] += shM[tid+off];
    }
    __syncthreads();
  }
  if (tid == 0) {
    atomicAdd(&sc->hub, shH[0]);
    atomicAdd(&sc->cosSum, shC[0]);
    atomicAdd(&sc->n1, shN[0]);
    atomicAdd(&sc->nmd, shM[0]);
    __threadfence();
    int d = atomicAdd(&sc->done2, 1);
    if (d == (int)gridDim.x - 1) {
      __threadfence();
      double th_hub = atomicAdd(&sc->hub, 0.0);
      double th_cos = atomicAdd(&sc->cosSum, 0.0);
      int n1 = atomicAdd(&sc->n1, 0);
      int nmd = atomicAdd(&sc->nmd, 0);
      double l1 = (n1 > 0) ? th_hub / fmax((double)n1 * 3.0, 1.0) : 0.0;
      double ld = (nmd > 0) ? (1.0 - th_cos / fmax((double)nmd, 1.0)) : 0.0;
      out[0] = (float)l1;
      out[1] = (float)ld;
    }
  }
}

extern "C" void kernel_launch(void* const* d_in, const int* in_sizes, int n_in,
                              void* d_out, int out_size, void* d_ws, size_t ws_size,
                              hipStream_t stream) {
  const float* pred  = (const float*)d_in[0];
  const float* grid  = (const float*)d_in[1];
  const int*   label = (const int*)d_in[2];
  const int*   batch = (const int*)d_in[3];
  int n = in_sizes[2];

  char* p = (char*)d_ws;
  auto take = [&](size_t bytes) -> char* {
    char* r = p;
    p += (bytes + 255) & ~(size_t)255;
    return r;
  };
  // ---- zero-init region (one hipMemsetAsync covers all of it) ----
  char* zbase = p;
  unsigned long long* vA = (unsigned long long*)take((size_t)SLOTS*8);
  unsigned long long* vB = (unsigned long long*)take((size_t)SLOTS*8);
  int*    lmask    = (int*)   take((size_t)SLOTS*4);
  int*    codeCnt  = (int*)   take(NCODE*4);
  int*    blCnt    = (int*)   take(16*4);
  float*  blSum    = (float*) take(48*4);
  int*    ghist    = (int*)   take((size_t)HB*4);
  Scalars* sc      = (Scalars*)take(sizeof(Scalars));
  size_t zbytes = (size_t)(p - zbase);
  // ---- uninitialized buffers ----
  float4* ctr      = (float4*)take((size_t)SLOTS*16);
  float4* pC       = (float4*)take((size_t)NCODE*CSTRIDE*16);
  float*  tgt      = (float*) take((size_t)n*3*4);
  float*  mag      = (float*) take((size_t)n*4);

  int nb = (n + 255) / 256;
  int nfb = (n + PPB - 1) / PPB;

  double vi = 0.99 * (double)(n - 1);
  int r0 = (int)vi;
  int r1 = r0 + 1; if (r1 > n - 1) r1 = n - 1;
  double tfrac = vi - (double)r0;

  hipMemsetAsync(zbase, 0, zbytes, stream);
  k_scatter<<<nb, 256, 0, stream>>>(grid, label, batch, vA, vB, lmask,
                                    blCnt, blSum, n);
  k_prep<<<NBLK, 256, 0, stream>>>(vA, vB, lmask, ctr, pC, codeCnt);
  k_targets_fb<<<nfb, 256, 0, stream>>>(grid, label, batch, ctr, blCnt, blSum,
                                        pC, codeCnt, tgt, mag, ghist, sc,
                                        n, nfb, r0, r1, tfrac);
  k_loss<<<nb, 256, 0, stream>>>(pred, grid, tgt, mag, sc, (float*)d_out, n);
}